// Round 1
// baseline (5867.812 us; speedup 1.0000x reference)
//
#include <hip/hip_runtime.h>

// ---------------------------------------------------------------------------
// NER LSTM (B=256,S=128,E=256,H=512,O=32) — one persistent kernel.
// 256 wgs (1/CU) x 256 threads. 8 independent batch groups (32 rows) x 32
// col-group wgs (16 h-dims x 4 gates). Recurrent weights resident in VGPRs as
// f16 MFMA B-fragments; h exchanged via f16 double buffers in d_ws with a
// per-group epoch barrier (device-scope atomics). 16x16x32 f16 MFMA, fp32
// accum; LSTM pointwise/softmax fp32. Decoder one-hot input = column gather.
// ---------------------------------------------------------------------------

#define BN 256
#define SN 128
#define EN 256
#define HN 512
#define ON 32
#define RG 32          // batch rows per group
#define NCG 32         // col-group wgs per group
#define NTHREADS 256
#define XSTR 264       // xe stage row stride (f16): 256 + 8 pad
#define HSTR 520       // h  stage row stride (f16): 512 + 8 pad

typedef _Float16 f16;
typedef _Float16 f16x8 __attribute__((ext_vector_type(8)));
typedef _Float16 f16x2 __attribute__((ext_vector_type(2)));
typedef float f32x4 __attribute__((ext_vector_type(4)));

__device__ __forceinline__ f32x4 MFMA16(f16x8 a, f16x8 b, f32x4 c) {
  return __builtin_amdgcn_mfma_f32_16x16x32_f16(a, b, c, 0, 0, 0);
}

__device__ __forceinline__ float sigf(float x) { return 1.0f / (1.0f + __expf(-x)); }

// Load B-fragment slice of W [4H x K] (row-major) for column `col`:
// lane holds W[col][kt*32 + quad*8 + j], j=0..7  (B[k][n], n=lane&15 in col).
template<int NKT>
__device__ __forceinline__ void loadW(const float* __restrict__ Wb, int K, int col, int quad,
                                      f16x8* dst) {
  #pragma unroll
  for (int kt = 0; kt < NKT; ++kt) {
    const float* p = Wb + (size_t)col * K + kt * 32 + quad * 8;
    f32x4 a = *(const f32x4*)p;
    f32x4 b = *(const f32x4*)(p + 4);
    f16x8 h;
    h[0] = (f16)a[0]; h[1] = (f16)a[1]; h[2] = (f16)a[2]; h[3] = (f16)a[3];
    h[4] = (f16)b[0]; h[5] = (f16)b[1]; h[6] = (f16)b[2]; h[7] = (f16)b[3];
    dst[kt] = h;
  }
}

// Stage a contiguous [RG x HN] f16 tile from global into padded LDS.
__device__ __forceinline__ void stageH(f16* dst, const f16* __restrict__ src, int tid) {
  #pragma unroll
  for (int j = 0; j < 8; ++j) {
    int eo = j * 2048 + tid * 8;          // 8 f16 = 16B per thread per iter
    int rr = eo >> 9, cc = eo & 511;
    *(f16x8*)&dst[rr * HSTR + cc] = *(const f16x8*)(src + eo);
  }
}

// acc[mt] += stage(rows mt*16..) x Wr   (A[m=lane&15][k=quad*8+j] layout)
template<int NKT>
__device__ __forceinline__ void matmulAcc(f32x4* acc, const f16* stage, int stride,
                                          const f16x8* Wr, int l16, int quad) {
  #pragma unroll
  for (int mt = 0; mt < 2; ++mt) {
    #pragma unroll
    for (int kt = 0; kt < NKT; ++kt) {
      f16x8 a = *(const f16x8*)&stage[(mt * 16 + l16) * stride + kt * 32 + quad * 8];
      acc[mt] = MFMA16(a, Wr[kt], acc[mt]);
    }
  }
}

// Per-group epoch barrier over NCG wgs. Slots poisoned negative (0xAA...) by
// harness, epochs start at 1, so no init store is needed.
__device__ __forceinline__ void group_barrier(int* slots, int g, int cg, int tid, int epoch) {
  __syncthreads();   // all waves done + their stores drained (vmcnt0 at barrier)
  if (tid < 64) {
    if (tid == 0)
      __hip_atomic_store(&slots[g * 64 + cg], epoch, __ATOMIC_RELEASE, __HIP_MEMORY_SCOPE_AGENT);
    for (;;) {
      int v = (tid < NCG)
                ? __hip_atomic_load(&slots[g * 64 + tid], __ATOMIC_RELAXED, __HIP_MEMORY_SCOPE_AGENT)
                : epoch;
      if (__all(v >= epoch)) break;
    }
    __builtin_amdgcn_fence(__ATOMIC_ACQUIRE, "agent");
  }
  __syncthreads();
}

// Gate exchange via LDS + fp32 LSTM pointwise + f16 h write to exchange buf.
// C/D layout: col=lane&15 (gate dim), row=quad*4+reg. Wave w owns gate w.
__device__ __forceinline__ void exchUpdate(const f32x4* acc, float* gb, int w, int quad, int l16,
                                           int urow, int ud0, float& ca, float& cb,
                                           f16* __restrict__ hout, int g, int cg) {
  #pragma unroll
  for (int mt = 0; mt < 2; ++mt) {
    #pragma unroll
    for (int i = 0; i < 4; ++i)
      gb[(mt * 16 + quad * 4 + i) * 64 + w * 16 + l16] = acc[mt][i];
  }
  __syncthreads();
  const float* gr = gb + urow * 64;
  float vi0 = gr[ud0],      vi1 = gr[ud0 + 1];
  float vf0 = gr[16 + ud0], vf1 = gr[16 + ud0 + 1];
  float vg0 = gr[32 + ud0], vg1 = gr[32 + ud0 + 1];
  float vo0 = gr[48 + ud0], vo1 = gr[48 + ud0 + 1];
  ca = sigf(vf0) * ca + sigf(vi0) * tanhf(vg0);
  cb = sigf(vf1) * cb + sigf(vi1) * tanhf(vg1);
  float ha = sigf(vo0) * tanhf(ca);
  float hb = sigf(vo1) * tanhf(cb);
  f16x2 hv; hv[0] = (f16)ha; hv[1] = (f16)hb;
  *(f16x2*)&hout[(size_t)(g * RG + urow) * HN + cg * 16 + ud0] = hv;
}

__launch_bounds__(NTHREADS, 1)
__global__ void lstm_all(const int* __restrict__ xTok, const float* __restrict__ emb,
    const float* __restrict__ eWih0, const float* __restrict__ eWhh0,
    const float* __restrict__ ebih0, const float* __restrict__ ebhh0,
    const float* __restrict__ eWih1, const float* __restrict__ eWhh1,
    const float* __restrict__ ebih1, const float* __restrict__ ebhh1,
    const float* __restrict__ dWih0, const float* __restrict__ dWhh0,
    const float* __restrict__ dbih0, const float* __restrict__ dbhh0,
    const float* __restrict__ dWih1, const float* __restrict__ dWhh1,
    const float* __restrict__ dbih1, const float* __restrict__ dbhh1,
    const float* __restrict__ fcw, const float* __restrict__ fcb,
    float* __restrict__ dout, f16* __restrict__ h0buf, f16* __restrict__ h1buf,
    int* __restrict__ slots)
{
  __shared__ __align__(16) char upool[RG * XSTR * 2];  // enc: xe stage | dec: lbuf + w0d
  __shared__ f16 h0s[RG * HSTR];
  __shared__ f16 h1s[RG * HSTR];
  __shared__ float gbuf[RG * 64];
  __shared__ int amaxlds[RG];

  f16*   xes  = (f16*)upool;
  float* lbuf = (float*)upool;            // [RG][33] logits (decoder only)
  float* w0d  = (float*)(upool + 4352);   // [64][32] dec_Wih0 slice (decoder only)

  const int tid  = threadIdx.x;
  const int g    = blockIdx.x & 7;        // batch group (XCD-affine if round-robin)
  const int cg   = blockIdx.x >> 3;       // col-group within group, 0..31
  const int w    = tid >> 6;              // wave = gate index 0..3
  const int lane = tid & 63;
  const int quad = lane >> 4;
  const int l16  = lane & 15;
  const int colg = w * HN + cg * 16 + l16;  // global gate column (2048-space)
  const int urow = tid >> 3;              // update: row 0..31
  const int ud0  = (tid & 7) * 2;         // update: dim pair 0,2,..,14
  int epoch = 0;

  // ---- encoder weights -> VGPR B-fragments (~224 VGPR/lane)
  f16x8 Wi0r[8], Wh0r[16], Wi1r[16], Wh1r[16];
  loadW<8>(eWih0, EN, colg, quad, Wi0r);
  loadW<16>(eWhh0, HN, colg, quad, Wh0r);
  loadW<16>(eWih1, HN, colg, quad, Wi1r);
  loadW<16>(eWhh1, HN, colg, quad, Wh1r);
  float bias0 = ebih0[colg] + ebhh0[colg];
  float bias1 = ebih1[colg] + ebhh1[colg];

  // ---- zero h(-1) (parity 1) for owned slice; zero cell state
  float c0a = 0.f, c0b = 0.f, c1a = 0.f, c1b = 0.f;
  {
    f16x2 z; z[0] = (f16)0.f; z[1] = (f16)0.f;
    size_t off = (size_t)BN * HN + (size_t)(g * RG + urow) * HN + cg * 16 + ud0;
    *(f16x2*)&h0buf[off] = z;
    *(f16x2*)&h1buf[off] = z;
  }
  group_barrier(slots, g, cg, tid, ++epoch);

  // ================= encoder: wavefront, interval k does cell0@k + cell1@(k-1)
  for (int k = 0; k <= SN; ++k) {
    if (k < SN) {   // stage xe(k): gather emb rows, cvt f16
      int r = tid >> 3, sub = tid & 7;
      int tok = xTok[(g * RG + r) * SN + k];
      const float* er = emb + (size_t)tok * EN + sub * 32;
      f16* dst = &xes[r * XSTR + sub * 32];
      #pragma unroll
      for (int jj = 0; jj < 32; jj += 8) {
        f32x4 a = *(const f32x4*)(er + jj);
        f32x4 b = *(const f32x4*)(er + jj + 4);
        f16x8 hv;
        hv[0] = (f16)a[0]; hv[1] = (f16)a[1]; hv[2] = (f16)a[2]; hv[3] = (f16)a[3];
        hv[4] = (f16)b[0]; hv[5] = (f16)b[1]; hv[6] = (f16)b[2]; hv[7] = (f16)b[3];
        *(f16x8*)(dst + jj) = hv;
      }
    }
    stageH(h0s, h0buf + (size_t)((k - 1) & 1) * BN * HN + (size_t)(g * RG) * HN, tid); // h0@(k-1)
    if (k >= 1)
      stageH(h1s, h1buf + (size_t)(k & 1) * BN * HN + (size_t)(g * RG) * HN, tid);     // h1@(k-2)
    __syncthreads();

    f32x4 acc0[2], acc1[2];
    if (k < SN) {   // cell0@k : xe@Wih0^T + h0@Whh0^T + b
      f32x4 b0; b0[0] = bias0; b0[1] = bias0; b0[2] = bias0; b0[3] = bias0;
      acc0[0] = b0; acc0[1] = b0;
      matmulAcc<8>(acc0, xes, XSTR, Wi0r, l16, quad);
      matmulAcc<16>(acc0, h0s, HSTR, Wh0r, l16, quad);
    }
    if (k >= 1) {   // cell1@(k-1) : h0@(k-1)@Wih1^T + h1@(k-2)@Whh1^T + b
      f32x4 b1; b1[0] = bias1; b1[1] = bias1; b1[2] = bias1; b1[3] = bias1;
      acc1[0] = b1; acc1[1] = b1;
      matmulAcc<16>(acc1, h0s, HSTR, Wi1r, l16, quad);
      matmulAcc<16>(acc1, h1s, HSTR, Wh1r, l16, quad);
    }
    if (k < SN)
      exchUpdate(acc0, gbuf, w, quad, l16, urow, ud0, c0a, c0b,
                 h0buf + (size_t)(k & 1) * BN * HN, g, cg);
    if (k >= 1) {
      __syncthreads();  // gbuf reuse guard
      exchUpdate(acc1, gbuf, w, quad, l16, urow, ud0, c1a, c1b,
                 h1buf + (size_t)((k - 1) & 1) * BN * HN, g, cg);
    }
    group_barrier(slots, g, cg, tid, ++epoch);
  }

  // ================= decoder setup: swap weight regs to decoder weights
  loadW<16>(dWhh0, HN, colg, quad, Wh0r);
  loadW<16>(dWih1, HN, colg, quad, Wi1r);
  loadW<16>(dWhh1, HN, colg, quad, Wh1r);
  bias0 = dbih0[colg] + dbhh0[colg];
  bias1 = dbih1[colg] + dbhh1[colg];
  {   // dec_Wih0 slice [64 owned cols][32 inputs] -> LDS (one-hot gather table)
    int cl = tid >> 2, i0 = (tid & 3) * 8;
    int gcol = (cl >> 4) * HN + cg * 16 + (cl & 15);
    const float* p = dWih0 + (size_t)gcol * ON + i0;
    #pragma unroll
    for (int j = 0; j < 8; ++j) w0d[cl * 32 + i0 + j] = p[j];
  }
  if (tid < RG) amaxlds[tid] = 0;   // xin(0) = one-hot(0)
  // note: h0s still holds h0@127 (staged at k=128); h1buf parity1 = h1@127.

  // ================= decoder: I1 = [fc+softmax+amax@(t-1)] + cell0@t ; I2 = cell1@t
  for (int t = 0; t <= SN; ++t) {
    stageH(h1s, h1buf + (size_t)((t - 1) & 1) * BN * HN + (size_t)(g * RG) * HN, tid); // h1@(t-1)
    __syncthreads();

    if (t >= 1) {
      int st = t - 1;
      int fmt = w & 1, fnt = w >> 1;
      int colo = fnt * 16 + l16;
      f32x4 afc;
      { float fb = fcb[st * ON + colo]; afc[0] = fb; afc[1] = fb; afc[2] = fb; afc[3] = fb; }
      #pragma unroll
      for (int kt = 0; kt < 16; ++kt) {   // B-frag from fp32 fc_w, inline cvt
        const float* p = fcw + ((size_t)st * ON + colo) * HN + kt * 32 + quad * 8;
        f32x4 a = *(const f32x4*)p;
        f32x4 b = *(const f32x4*)(p + 4);
        f16x8 bf;
        bf[0] = (f16)a[0]; bf[1] = (f16)a[1]; bf[2] = (f16)a[2]; bf[3] = (f16)a[3];
        bf[4] = (f16)b[0]; bf[5] = (f16)b[1]; bf[6] = (f16)b[2]; bf[7] = (f16)b[3];
        f16x8 av = *(const f16x8*)&h1s[(fmt * 16 + l16) * HSTR + kt * 32 + quad * 8];
        afc = MFMA16(av, bf, afc);
      }
      #pragma unroll
      for (int i = 0; i < 4; ++i)
        lbuf[(fmt * 16 + quad * 4 + i) * 33 + colo] = afc[i];
      __syncthreads();
      if (tid < RG) {   // per-row softmax + argmax (first-max semantics)
        float mx = lbuf[tid * 33]; int bi = 0;
        #pragma unroll
        for (int c = 1; c < ON; ++c) { float v = lbuf[tid * 33 + c]; if (v > mx) { mx = v; bi = c; } }
        float ss = 0.f;
        #pragma unroll
        for (int c = 0; c < ON; ++c) ss += __expf(lbuf[tid * 33 + c] - mx);
        amaxlds[tid] = bi;
        if (cg == 0) {
          float inv = 1.0f / ss;
          float* op = dout + ((size_t)(g * RG + tid) * SN + st) * ON;
          #pragma unroll
          for (int c = 0; c < ON; ++c) op[c] = __expf(lbuf[tid * 33 + c] - mx) * inv;
        }
      }
      __syncthreads();
    }

    if (t < SN) {   // cell0@t : gather(dec_Wih0, amax) + h0@(t-1)@Whh0^T + b
      f32x4 acc0[2];
      #pragma unroll
      for (int mt = 0; mt < 2; ++mt) {
        #pragma unroll
        for (int i = 0; i < 4; ++i) {
          int row = mt * 16 + quad * 4 + i;
          acc0[mt][i] = bias0 + w0d[(w * 16 + l16) * 32 + amaxlds[row]];
        }
      }
      matmulAcc<16>(acc0, h0s, HSTR, Wh0r, l16, quad);
      exchUpdate(acc0, gbuf, w, quad, l16, urow, ud0, c0a, c0b,
                 h0buf + (size_t)(t & 1) * BN * HN, g, cg);
    }
    group_barrier(slots, g, cg, tid, ++epoch);

    if (t < SN) {   // I2: cell1@t : h0@t@Wih1^T + h1@(t-1)@Whh1^T + b
      stageH(h0s, h0buf + (size_t)(t & 1) * BN * HN + (size_t)(g * RG) * HN, tid);
      __syncthreads();
      f32x4 acc1[2];
      f32x4 b1; b1[0] = bias1; b1[1] = bias1; b1[2] = bias1; b1[3] = bias1;
      acc1[0] = b1; acc1[1] = b1;
      matmulAcc<16>(acc1, h0s, HSTR, Wi1r, l16, quad);
      matmulAcc<16>(acc1, h1s, HSTR, Wh1r, l16, quad);
      exchUpdate(acc1, gbuf, w, quad, l16, urow, ud0, c1a, c1b,
                 h1buf + (size_t)(t & 1) * BN * HN, g, cg);
      group_barrier(slots, g, cg, tid, ++epoch);
    }
  }
}

extern "C" void kernel_launch(void* const* d_in, const int* in_sizes, int n_in,
                              void* d_out, int out_size, void* d_ws, size_t ws_size,
                              hipStream_t stream) {
  (void)in_sizes; (void)n_in; (void)out_size; (void)ws_size;
  const int*   xTok  = (const int*)d_in[0];
  const float* emb   = (const float*)d_in[1];
  const float* eWih0 = (const float*)d_in[2];
  const float* eWhh0 = (const float*)d_in[3];
  const float* ebih0 = (const float*)d_in[4];
  const float* ebhh0 = (const float*)d_in[5];
  const float* eWih1 = (const float*)d_in[6];
  const float* eWhh1 = (const float*)d_in[7];
  const float* ebih1 = (const float*)d_in[8];
  const float* ebhh1 = (const float*)d_in[9];
  const float* dWih0 = (const float*)d_in[10];
  const float* dWhh0 = (const float*)d_in[11];
  const float* dbih0 = (const float*)d_in[12];
  const float* dbhh0 = (const float*)d_in[13];
  const float* dWih1 = (const float*)d_in[14];
  const float* dWhh1 = (const float*)d_in[15];
  const float* dbih1 = (const float*)d_in[16];
  const float* dbhh1 = (const float*)d_in[17];
  const float* fcw   = (const float*)d_in[18];
  const float* fcb   = (const float*)d_in[19];

  // ws layout: h0buf [2][256][512] f16 (512KB) | h1buf (512KB) | slots [8][64] int (2KB)
  f16* h0buf = (f16*)d_ws;
  f16* h1buf = (f16*)((char*)d_ws + (size_t)2 * BN * HN * sizeof(f16));
  int* slots = (int*)((char*)d_ws + (size_t)4 * BN * HN * sizeof(f16));

  hipLaunchKernelGGL(lstm_all, dim3(256), dim3(NTHREADS), 0, stream,
                     xTok, emb, eWih0, eWhh0, ebih0, ebhh0, eWih1, eWhh1, ebih1, ebhh1,
                     dWih0, dWhh0, dbih0, dbhh0, dWih1, dWhh1, dbih1, dbhh1,
                     fcw, fcb, (float*)d_out, h0buf, h1buf, slots);
}

// Round 2
// 5142.635 us; speedup vs baseline: 1.1410x; 1.1410x over previous
//
#include <hip/hip_runtime.h>

// ---------------------------------------------------------------------------
// NER LSTM (B=256,S=128,E=256,H=512,O=32) — one persistent kernel.
// 256 wgs x 256 threads. 8 batch groups (32 rows) x 32 col-group wgs.
// Recurrent weights resident in VGPRs as f16 MFMA B-fragments.
// R2 change: NO acquire/release fences (they emit buffer_wbl2/buffer_inv =
// full L2 flush per barrier -> 15us/interval in R1). All cross-wg exchange
// (h tiles, barrier flags) uses relaxed AGENT-scope atomics (sc1: coherent at
// MALL, bypass L2) so the L2 stays warm for emb/fcw/weights. Barrier release
// relies on vmcnt(0) drain (compiler emits it before s_barrier) + relaxed
// flag store; pollers use relaxed atomic loads + s_sleep backoff.
// ---------------------------------------------------------------------------

#define BN 256
#define SN 128
#define EN 256
#define HN 512
#define ON 32
#define RG 32          // batch rows per group
#define NCG 32         // col-group wgs per group
#define NTHREADS 256
#define XSTR 264       // xe stage row stride (f16): 256 + 8 pad
#define HSTR 520       // h  stage row stride (f16): 512 + 8 pad
#define GSTR 68        // gbuf row stride (floats): 64 + 4 pad (bank spread)
#define HU   128       // 8B units per h row (512 f16 / 4)

typedef _Float16 f16;
typedef _Float16 f16x8 __attribute__((ext_vector_type(8)));
typedef _Float16 f16x4 __attribute__((ext_vector_type(4)));
typedef float f32x4 __attribute__((ext_vector_type(4)));
typedef unsigned long long u64;

union U64F16 { u64 u; f16x4 h; };

__device__ __forceinline__ f32x4 MFMA16(f16x8 a, f16x8 b, f32x4 c) {
  return __builtin_amdgcn_mfma_f32_16x16x32_f16(a, b, c, 0, 0, 0);
}

__device__ __forceinline__ float sigf(float x) { return 1.0f / (1.0f + __expf(-x)); }

// Load B-fragment slice of W [4H x K] (row-major) for column `col`:
// lane holds W[col][kt*32 + quad*8 + j], j=0..7.
template<int NKT>
__device__ __forceinline__ void loadW(const float* __restrict__ Wb, int K, int col, int quad,
                                      f16x8* dst) {
  #pragma unroll
  for (int kt = 0; kt < NKT; ++kt) {
    const float* p = Wb + (size_t)col * K + kt * 32 + quad * 8;
    f32x4 a = *(const f32x4*)p;
    f32x4 b = *(const f32x4*)(p + 4);
    f16x8 h;
    h[0] = (f16)a[0]; h[1] = (f16)a[1]; h[2] = (f16)a[2]; h[3] = (f16)a[3];
    h[4] = (f16)b[0]; h[5] = (f16)b[1]; h[6] = (f16)b[2]; h[7] = (f16)b[3];
    dst[kt] = h;
  }
}

// Stage [RG x HN] f16 tile from MALL-coherent exchange buf into padded LDS.
__device__ __forceinline__ void stageH(f16* dst, const u64* __restrict__ src, int tid) {
  #pragma unroll
  for (int j = 0; j < 16; ++j) {
    int u = j * 256 + tid;          // 8B unit index, coalesced per wave
    int rr = u >> 7, cc = u & 127;
    u64 v = __hip_atomic_load(src + u, __ATOMIC_RELAXED, __HIP_MEMORY_SCOPE_AGENT);
    *(u64*)&dst[rr * HSTR + cc * 4] = v;
  }
}

// acc[mt] += stage(rows mt*16..) x Wr   (A[m=lane&15][k=quad*8+j] layout)
template<int NKT>
__device__ __forceinline__ void matmulAcc(f32x4* acc, const f16* stage, int stride,
                                          const f16x8* Wr, int l16, int quad) {
  #pragma unroll
  for (int mt = 0; mt < 2; ++mt) {
    #pragma unroll
    for (int kt = 0; kt < NKT; ++kt) {
      f16x8 a = *(const f16x8*)&stage[(mt * 16 + l16) * stride + kt * 32 + quad * 8];
      acc[mt] = MFMA16(a, Wr[kt], acc[mt]);
    }
  }
}

// Per-group epoch barrier over NCG wgs — fence-free.
// Entry __syncthreads carries compiler-emitted s_waitcnt vmcnt(0): every
// wave's sc1 h-stores are complete (visible at MALL) before any flag store.
__device__ __forceinline__ void group_barrier(int* slots, int g, int cg, int tid, int epoch) {
  __syncthreads();
  if (tid < 64) {
    if (tid == 0) {
      __builtin_amdgcn_s_waitcnt(0);
      __hip_atomic_store(&slots[g * 64 + cg], epoch, __ATOMIC_RELAXED, __HIP_MEMORY_SCOPE_AGENT);
    }
    for (;;) {
      int v = (tid < NCG)
                ? __hip_atomic_load(&slots[g * 64 + tid], __ATOMIC_RELAXED, __HIP_MEMORY_SCOPE_AGENT)
                : epoch;
      if (__all(v >= epoch)) break;
      __builtin_amdgcn_s_sleep(1);
    }
  }
  __syncthreads();
  asm volatile("" ::: "memory");
}

// Gate exchange via LDS + fp32 LSTM pointwise + packed f16x4 coherent h store.
// C/D layout: col=lane&15 (gate dim), row=quad*4+reg. Wave w owns gate w.
// Caller must ensure gbuf is not still being read (syncthreads before reuse).
__device__ __forceinline__ void exchUpdate(const f32x4* acc, float* gb, int w, int quad, int l16,
                                           int tid, float* cv, u64* __restrict__ hout,
                                           int g, int cg) {
  #pragma unroll
  for (int mt = 0; mt < 2; ++mt) {
    #pragma unroll
    for (int i = 0; i < 4; ++i)
      gb[(mt * 16 + quad * 4 + i) * GSTR + w * 16 + l16] = acc[mt][i];
  }
  __syncthreads();
  if (tid < 128) {
    int urow = tid >> 2, uu = tid & 3;     // row 0..31, 4-dim unit 0..3
    const float* gr = gb + urow * GSTR + uu * 4;
    U64F16 hv;
    #pragma unroll
    for (int j = 0; j < 4; ++j) {
      float vi = gr[j], vf = gr[16 + j], vg = gr[32 + j], vo = gr[48 + j];
      cv[j] = sigf(vf) * cv[j] + sigf(vi) * tanhf(vg);
      hv.h[j] = (f16)(sigf(vo) * tanhf(cv[j]));
    }
    __hip_atomic_store(hout + (size_t)(g * RG + urow) * HU + cg * 4 + uu, hv.u,
                       __ATOMIC_RELAXED, __HIP_MEMORY_SCOPE_AGENT);
  }
}

__launch_bounds__(NTHREADS, 1)
__global__ void lstm_all(const int* __restrict__ xTok, const float* __restrict__ emb,
    const float* __restrict__ eWih0, const float* __restrict__ eWhh0,
    const float* __restrict__ ebih0, const float* __restrict__ ebhh0,
    const float* __restrict__ eWih1, const float* __restrict__ eWhh1,
    const float* __restrict__ ebih1, const float* __restrict__ ebhh1,
    const float* __restrict__ dWih0, const float* __restrict__ dWhh0,
    const float* __restrict__ dbih0, const float* __restrict__ dbhh0,
    const float* __restrict__ dWih1, const float* __restrict__ dWhh1,
    const float* __restrict__ dbih1, const float* __restrict__ dbhh1,
    const float* __restrict__ fcw, const float* __restrict__ fcb,
    float* __restrict__ dout, u64* __restrict__ h0buf, u64* __restrict__ h1buf,
    int* __restrict__ slots)
{
  __shared__ __align__(16) char upool[RG * XSTR * 2];  // enc: xe stage | dec: lbuf + w0d
  __shared__ __align__(16) f16 h0s[RG * HSTR];
  __shared__ __align__(16) f16 h1s[RG * HSTR];
  __shared__ float gbuf[RG * GSTR];
  __shared__ int amaxlds[RG];

  f16*   xes  = (f16*)upool;
  float* lbuf = (float*)upool;            // [RG][33] logits (decoder only)
  float* w0d  = (float*)(upool + 4352);   // [64][32] dec_Wih0 slice (decoder only)

  const int tid  = threadIdx.x;
  const int g    = blockIdx.x & 7;        // batch group (XCD-affine if round-robin)
  const int cg   = blockIdx.x >> 3;       // col-group within group, 0..31
  const int w    = tid >> 6;              // wave = gate index 0..3
  const int lane = tid & 63;
  const int quad = lane >> 4;
  const int l16  = lane & 15;
  const int colg = w * HN + cg * 16 + l16;  // global gate column (2048-space)
  int epoch = 0;

  // ---- encoder weights -> VGPR B-fragments
  f16x8 Wi0r[8], Wh0r[16], Wi1r[16], Wh1r[16];
  loadW<8>(eWih0, EN, colg, quad, Wi0r);
  loadW<16>(eWhh0, HN, colg, quad, Wh0r);
  loadW<16>(eWih1, HN, colg, quad, Wi1r);
  loadW<16>(eWhh1, HN, colg, quad, Wh1r);
  float bias0 = ebih0[colg] + ebhh0[colg];
  float bias1 = ebih1[colg] + ebhh1[colg];

  // ---- zero h(-1) (parity 1); zero cell state (per-thread 4 dims, tid<128)
  float c0[4] = {0.f, 0.f, 0.f, 0.f}, c1[4] = {0.f, 0.f, 0.f, 0.f};
  if (tid < 128) {
    int urow = tid >> 2, uu = tid & 3;
    size_t off = (size_t)BN * HU + (size_t)(g * RG + urow) * HU + cg * 4 + uu;
    __hip_atomic_store(h0buf + off, 0ull, __ATOMIC_RELAXED, __HIP_MEMORY_SCOPE_AGENT);
    __hip_atomic_store(h1buf + off, 0ull, __ATOMIC_RELAXED, __HIP_MEMORY_SCOPE_AGENT);
  }
  group_barrier(slots, g, cg, tid, ++epoch);

  // ================= encoder: wavefront, interval k does cell0@k + cell1@(k-1)
  for (int k = 0; k <= SN; ++k) {
    if (k < SN) {   // stage xe(k): gather emb rows (plain loads, L2-warm), cvt f16
      int r = tid >> 3, sub = tid & 7;
      int tok = xTok[(g * RG + r) * SN + k];
      const float* er = emb + (size_t)tok * EN + sub * 32;
      f16* dst = &xes[r * XSTR + sub * 32];
      #pragma unroll
      for (int jj = 0; jj < 32; jj += 8) {
        f32x4 a = *(const f32x4*)(er + jj);
        f32x4 b = *(const f32x4*)(er + jj + 4);
        f16x8 hv;
        hv[0] = (f16)a[0]; hv[1] = (f16)a[1]; hv[2] = (f16)a[2]; hv[3] = (f16)a[3];
        hv[4] = (f16)b[0]; hv[5] = (f16)b[1]; hv[6] = (f16)b[2]; hv[7] = (f16)b[3];
        *(f16x8*)(dst + jj) = hv;
      }
    }
    stageH(h0s, h0buf + (size_t)((k - 1) & 1) * BN * HU + (size_t)(g * RG) * HU, tid); // h0@(k-1)
    if (k >= 1)
      stageH(h1s, h1buf + (size_t)(k & 1) * BN * HU + (size_t)(g * RG) * HU, tid);     // h1@(k-2)
    __syncthreads();

    f32x4 acc0[2], acc1[2];
    if (k < SN) {   // cell0@k : xe@Wih0^T + h0@Whh0^T + b
      f32x4 b0; b0[0] = bias0; b0[1] = bias0; b0[2] = bias0; b0[3] = bias0;
      acc0[0] = b0; acc0[1] = b0;
      matmulAcc<8>(acc0, xes, XSTR, Wi0r, l16, quad);
      matmulAcc<16>(acc0, h0s, HSTR, Wh0r, l16, quad);
    }
    if (k >= 1) {   // cell1@(k-1) : h0@(k-1)@Wih1^T + h1@(k-2)@Whh1^T + b
      f32x4 b1; b1[0] = bias1; b1[1] = bias1; b1[2] = bias1; b1[3] = bias1;
      acc1[0] = b1; acc1[1] = b1;
      matmulAcc<16>(acc1, h0s, HSTR, Wi1r, l16, quad);
      matmulAcc<16>(acc1, h1s, HSTR, Wh1r, l16, quad);
    }
    if (k < SN)
      exchUpdate(acc0, gbuf, w, quad, l16, tid, c0,
                 h0buf + (size_t)(k & 1) * BN * HU, g, cg);
    if (k >= 1) {
      __syncthreads();  // gbuf reuse guard
      exchUpdate(acc1, gbuf, w, quad, l16, tid, c1,
                 h1buf + (size_t)((k - 1) & 1) * BN * HU, g, cg);
    }
    group_barrier(slots, g, cg, tid, ++epoch);
  }

  // ================= decoder setup: swap weight regs to decoder weights
  loadW<16>(dWhh0, HN, colg, quad, Wh0r);
  loadW<16>(dWih1, HN, colg, quad, Wi1r);
  loadW<16>(dWhh1, HN, colg, quad, Wh1r);
  bias0 = dbih0[colg] + dbhh0[colg];
  bias1 = dbih1[colg] + dbhh1[colg];
  {   // dec_Wih0 slice [64 owned cols][32 inputs] -> LDS (one-hot gather table)
    int cl = tid >> 2, i0 = (tid & 3) * 8;
    int gcol = (cl >> 4) * HN + cg * 16 + (cl & 15);
    const float* p = dWih0 + (size_t)gcol * ON + i0;
    #pragma unroll
    for (int j = 0; j < 8; ++j) w0d[cl * 32 + i0 + j] = p[j];
  }
  if (tid < RG) amaxlds[tid] = 0;   // xin(0) = one-hot(0)
  // note: h0s still holds h0@127 (staged at k=128); h1buf parity1 = h1@127.
  // cell states c0,c1 carry over from encoder finals (reference semantics).

  // ================= decoder: I1 = [fc+softmax+amax@(t-1)] + cell0@t ; I2 = cell1@t
  for (int t = 0; t <= SN; ++t) {
    stageH(h1s, h1buf + (size_t)((t - 1) & 1) * BN * HU + (size_t)(g * RG) * HU, tid); // h1@(t-1)
    __syncthreads();

    if (t >= 1) {
      int st = t - 1;
      int fmt = w & 1, fnt = w >> 1;
      int colo = fnt * 16 + l16;
      f32x4 afc;
      { float fb = fcb[st * ON + colo]; afc[0] = fb; afc[1] = fb; afc[2] = fb; afc[3] = fb; }
      #pragma unroll
      for (int kt = 0; kt < 16; ++kt) {   // B-frag from fp32 fc_w (L2-warm), inline cvt
        const float* p = fcw + ((size_t)st * ON + colo) * HN + kt * 32 + quad * 8;
        f32x4 a = *(const f32x4*)p;
        f32x4 b = *(const f32x4*)(p + 4);
        f16x8 bf;
        bf[0] = (f16)a[0]; bf[1] = (f16)a[1]; bf[2] = (f16)a[2]; bf[3] = (f16)a[3];
        bf[4] = (f16)b[0]; bf[5] = (f16)b[1]; bf[6] = (f16)b[2]; bf[7] = (f16)b[3];
        f16x8 av = *(const f16x8*)&h1s[(fmt * 16 + l16) * HSTR + kt * 32 + quad * 8];
        afc = MFMA16(av, bf, afc);
      }
      #pragma unroll
      for (int i = 0; i < 4; ++i)
        lbuf[(fmt * 16 + quad * 4 + i) * 33 + colo] = afc[i];
      __syncthreads();
      if (tid < RG) {   // per-row softmax + argmax (first-max semantics)
        float mx = lbuf[tid * 33]; int bi = 0;
        #pragma unroll
        for (int c = 1; c < ON; ++c) { float v = lbuf[tid * 33 + c]; if (v > mx) { mx = v; bi = c; } }
        float ss = 0.f;
        #pragma unroll
        for (int c = 0; c < ON; ++c) ss += __expf(lbuf[tid * 33 + c] - mx);
        amaxlds[tid] = bi;
        if (cg == 0) {
          float inv = 1.0f / ss;
          float* op = dout + ((size_t)(g * RG + tid) * SN + st) * ON;
          #pragma unroll
          for (int c = 0; c < ON; ++c) op[c] = __expf(lbuf[tid * 33 + c] - mx) * inv;
        }
      }
      __syncthreads();
    }

    if (t < SN) {   // cell0@t : gather(dec_Wih0, amax) + h0@(t-1)@Whh0^T + b
      f32x4 acc0[2];
      #pragma unroll
      for (int mt = 0; mt < 2; ++mt) {
        #pragma unroll
        for (int i = 0; i < 4; ++i) {
          int row = mt * 16 + quad * 4 + i;
          acc0[mt][i] = bias0 + w0d[(w * 16 + l16) * 32 + amaxlds[row]];
        }
      }
      matmulAcc<16>(acc0, h0s, HSTR, Wh0r, l16, quad);
      exchUpdate(acc0, gbuf, w, quad, l16, tid, c0,
                 h0buf + (size_t)(t & 1) * BN * HU, g, cg);
    }
    group_barrier(slots, g, cg, tid, ++epoch);

    if (t < SN) {   // I2: cell1@t : h0@t@Wih1^T + h1@(t-1)@Whh1^T + b
      stageH(h0s, h0buf + (size_t)(t & 1) * BN * HU + (size_t)(g * RG) * HU, tid);
      __syncthreads();
      f32x4 acc1[2];
      f32x4 b1; b1[0] = bias1; b1[1] = bias1; b1[2] = bias1; b1[3] = bias1;
      acc1[0] = b1; acc1[1] = b1;
      matmulAcc<16>(acc1, h0s, HSTR, Wi1r, l16, quad);
      matmulAcc<16>(acc1, h1s, HSTR, Wh1r, l16, quad);
      exchUpdate(acc1, gbuf, w, quad, l16, tid, c1,
                 h1buf + (size_t)(t & 1) * BN * HU, g, cg);
      group_barrier(slots, g, cg, tid, ++epoch);
    }
  }
}

extern "C" void kernel_launch(void* const* d_in, const int* in_sizes, int n_in,
                              void* d_out, int out_size, void* d_ws, size_t ws_size,
                              hipStream_t stream) {
  (void)in_sizes; (void)n_in; (void)out_size; (void)ws_size;
  const int*   xTok  = (const int*)d_in[0];
  const float* emb   = (const float*)d_in[1];
  const float* eWih0 = (const float*)d_in[2];
  const float* eWhh0 = (const float*)d_in[3];
  const float* ebih0 = (const float*)d_in[4];
  const float* ebhh0 = (const float*)d_in[5];
  const float* eWih1 = (const float*)d_in[6];
  const float* eWhh1 = (const float*)d_in[7];
  const float* ebih1 = (const float*)d_in[8];
  const float* ebhh1 = (const float*)d_in[9];
  const float* dWih0 = (const float*)d_in[10];
  const float* dWhh0 = (const float*)d_in[11];
  const float* dbih0 = (const float*)d_in[12];
  const float* dbhh0 = (const float*)d_in[13];
  const float* dWih1 = (const float*)d_in[14];
  const float* dWhh1 = (const float*)d_in[15];
  const float* dbih1 = (const float*)d_in[16];
  const float* dbhh1 = (const float*)d_in[17];
  const float* fcw   = (const float*)d_in[18];
  const float* fcb   = (const float*)d_in[19];

  // ws layout: h0buf [2][256][128] u64 (512KB) | h1buf (512KB) | slots [8][64] int
  u64* h0buf = (u64*)d_ws;
  u64* h1buf = (u64*)((char*)d_ws + (size_t)2 * BN * HU * sizeof(u64));
  int* slots = (int*)((char*)d_ws + (size_t)4 * BN * HU * sizeof(u64));

  hipLaunchKernelGGL(lstm_all, dim3(256), dim3(NTHREADS), 0, stream,
                     xTok, emb, eWih0, eWhh0, ebih0, ebhh0, eWih1, eWhh1, ebih1, ebhh1,
                     dWih0, dWhh0, dbih0, dbhh0, dWih1, dWhh1, dbih1, dbhh1,
                     fcw, fcb, (float*)d_out, h0buf, h1buf, slots);
}

// Round 5
// 3055.325 us; speedup vs baseline: 1.9205x; 1.6832x over previous
//
#include <hip/hip_runtime.h>

// ---------------------------------------------------------------------------
// NER LSTM (B=256,S=128,E=256,H=512,O=32) — one persistent kernel.
// 256 wgs x 256 threads, 1 block/CU (92KB LDS). 8 batch groups (32 rows) x
// 32 col-group wgs (g=blockIdx&7 — R2-proven). Recurrent weights in VGPRs as
// f16 MFMA B-fragments. Exchange transport = R2-proven sc1/MALL relaxed
// atomics (R3/R4 showed the XCD-local sc0 protocol does NOT propagate).
// R5 changes vs R2 (attribution-clean):
//  1. stageH: batched plain `global_load_dwordx4 ... sc1` asm (MALL-coherent,
//     same semantics as relaxed agent atomic) — 1 waitcnt per stage instead
//     of 16 serialized atomic loads (~8us -> ~1us per interval).
//  2. Barrier split arrive/wait; next-step emb gather in the gap (encoder).
//  3. Latching escape guard: a deadlock degrades to fast garbage, not a hang.
// ---------------------------------------------------------------------------

#define BN 256
#define SN 128
#define EN 256
#define HN 512
#define ON 32
#define RG 32          // batch rows per group
#define NCG 32         // col-group wgs per group
#define NTHREADS 256
#define XSTR 264       // xe stage row stride (f16): 256 + 8 pad
#define HSTR 520       // h  stage row stride (f16): 512 + 8 pad
#define GSTR 68        // gbuf row stride (floats): 64 + 4 pad
#define POLL_GUARD (1 << 20)

typedef _Float16 f16;
typedef _Float16 f16x8 __attribute__((ext_vector_type(8)));
typedef _Float16 f16x2 __attribute__((ext_vector_type(2)));
typedef float f32x4 __attribute__((ext_vector_type(4)));
typedef unsigned u32x4 __attribute__((ext_vector_type(4)));
typedef unsigned long long u64;

__device__ __forceinline__ f32x4 MFMA16(f16x8 a, f16x8 b, f32x4 c) {
  return __builtin_amdgcn_mfma_f32_16x16x32_f16(a, b, c, 0, 0, 0);
}

__device__ __forceinline__ float sigf(float x) { return 1.0f / (1.0f + __expf(-x)); }

// Load B-fragment slice of W [4H x K] (row-major) for column `col`:
// lane holds W[col][kt*32 + quad*8 + j], j=0..7.
template<int NKT>
__device__ __forceinline__ void loadW(const float* __restrict__ Wb, int K, int col, int quad,
                                      f16x8* dst) {
  #pragma unroll
  for (int kt = 0; kt < NKT; ++kt) {
    const float* p = Wb + (size_t)col * K + kt * 32 + quad * 8;
    f32x4 a = *(const f32x4*)p;
    f32x4 b = *(const f32x4*)(p + 4);
    f16x8 h;
    h[0] = (f16)a[0]; h[1] = (f16)a[1]; h[2] = (f16)a[2]; h[3] = (f16)a[3];
    h[4] = (f16)b[0]; h[5] = (f16)b[1]; h[6] = (f16)b[2]; h[7] = (f16)b[3];
    dst[kt] = h;
  }
}

// Stage ONE [RG x HN] f16 tile (32KB) from the MALL-coherent exchange buffer
// into padded LDS. 8 batched dwordx4 sc1 loads per thread, single waitcnt.
__device__ __forceinline__ void stage1(f16* dst, const char* __restrict__ src, int tid) {
  u32x4 v[8];
  const char* base = src + tid * 16;
  #pragma unroll
  for (int j = 0; j < 8; ++j)
    asm volatile("global_load_dwordx4 %0, %1, off sc1" : "=v"(v[j]) : "v"(base + j * 4096));
  asm volatile("s_waitcnt vmcnt(0)" ::: "memory");
  #pragma unroll
  for (int j = 0; j < 8; ++j) {
    int u = j * 256 + tid, rr = u >> 6, cc = u & 63;
    *(u32x4*)&dst[rr * HSTR + cc * 8] = v[j];
  }
}

// Stage TWO tiles with one shared waitcnt (both round-trips overlap).
__device__ __forceinline__ void stage2(f16* d0, const char* __restrict__ s0,
                                       f16* d1, const char* __restrict__ s1, int tid) {
  u32x4 v0[8], v1[8];
  const char* b0 = s0 + tid * 16;
  const char* b1 = s1 + tid * 16;
  #pragma unroll
  for (int j = 0; j < 8; ++j)
    asm volatile("global_load_dwordx4 %0, %1, off sc1" : "=v"(v0[j]) : "v"(b0 + j * 4096));
  #pragma unroll
  for (int j = 0; j < 8; ++j)
    asm volatile("global_load_dwordx4 %0, %1, off sc1" : "=v"(v1[j]) : "v"(b1 + j * 4096));
  asm volatile("s_waitcnt vmcnt(0)" ::: "memory");
  #pragma unroll
  for (int j = 0; j < 8; ++j) {
    int u = j * 256 + tid, rr = u >> 6, cc = u & 63;
    *(u32x4*)&d0[rr * HSTR + cc * 8] = v0[j];
    *(u32x4*)&d1[rr * HSTR + cc * 8] = v1[j];
  }
}

// acc[mt] += stage(rows mt*16..) x Wr   (A[m=lane&15][k=quad*8+j] layout)
template<int NKT>
__device__ __forceinline__ void matmulAcc(f32x4* acc, const f16* stage, int stride,
                                          const f16x8* Wr, int l16, int quad) {
  #pragma unroll
  for (int mt = 0; mt < 2; ++mt) {
    #pragma unroll
    for (int kt = 0; kt < NKT; ++kt) {
      f16x8 a = *(const f16x8*)&stage[(mt * 16 + l16) * stride + kt * 32 + quad * 8];
      acc[mt] = MFMA16(a, Wr[kt], acc[mt]);
    }
  }
}

// Barrier arrive: leading __syncthreads carries each wave's vmcnt(0) drain,
// so all sc1 h-stores are MALL-visible before the flag store.
__device__ __forceinline__ void barrier_arrive(int* slots, int g, int cg, int tid, int epoch) {
  __syncthreads();
  if (tid == 0) {
    asm volatile("s_waitcnt vmcnt(0)" ::: "memory");
    __hip_atomic_store(&slots[g * 64 + cg], epoch, __ATOMIC_RELAXED, __HIP_MEMORY_SCOPE_AGENT);
  }
}

// Barrier wait: wave0 polls the group's 32 flags (one 128B line) via relaxed
// agent atomics. Escape guard latches in LDS -> future barriers no-op.
__device__ __forceinline__ void barrier_wait(int* slots, int g, int tid, int epoch, int* esc) {
  if (tid < 64 && !*esc) {
    int gd = 0;
    for (;;) {
      int v = (tid < NCG)
                ? __hip_atomic_load(&slots[g * 64 + tid], __ATOMIC_RELAXED, __HIP_MEMORY_SCOPE_AGENT)
                : epoch;
      if (__all(v >= epoch)) break;
      if (++gd > POLL_GUARD) { if (tid == 0) *esc = 1; break; }
      __builtin_amdgcn_s_sleep(1);
    }
  }
  __syncthreads();
  asm volatile("" ::: "memory");
}

// Gather one time-step of embeddings for the group's 32 rows -> xes (f16).
__device__ __forceinline__ void gatherXE(f16* xes, const int* __restrict__ xTok,
                                         const float* __restrict__ emb, int g, int k, int tid) {
  int r = tid >> 3, sub = tid & 7;
  int tok = xTok[(g * RG + r) * SN + k];
  const float* er = emb + (size_t)tok * EN + sub * 32;
  f16* dst = &xes[r * XSTR + sub * 32];
  #pragma unroll
  for (int jj = 0; jj < 32; jj += 8) {
    f32x4 a = *(const f32x4*)(er + jj);
    f32x4 b = *(const f32x4*)(er + jj + 4);
    f16x8 hv;
    hv[0] = (f16)a[0]; hv[1] = (f16)a[1]; hv[2] = (f16)a[2]; hv[3] = (f16)a[3];
    hv[4] = (f16)b[0]; hv[5] = (f16)b[1]; hv[6] = (f16)b[2]; hv[7] = (f16)b[3];
    *(f16x8*)(dst + jj) = hv;
  }
}

// Gate exchange via LDS + fp32 LSTM pointwise + packed f16x2 sc1 h store.
// C/D layout: col=lane&15 (gate dim), row=quad*4+reg. Wave w owns gate w.
__device__ __forceinline__ void exchUpdate(const f32x4* acc, float* gb, int w, int quad, int l16,
                                           int tid, float* cv, unsigned* __restrict__ hout,
                                           int g, int cg) {
  #pragma unroll
  for (int mt = 0; mt < 2; ++mt) {
    #pragma unroll
    for (int i = 0; i < 4; ++i)
      gb[(mt * 16 + quad * 4 + i) * GSTR + w * 16 + l16] = acc[mt][i];
  }
  __syncthreads();
  {
    int row = tid >> 3, d0 = (tid & 7) * 2;
    const float* gr = gb + row * GSTR + d0;
    union { unsigned u; f16x2 h; } hv;
    #pragma unroll
    for (int j = 0; j < 2; ++j) {
      float vi = gr[j], vf = gr[16 + j], vg = gr[32 + j], vo = gr[48 + j];
      cv[j] = sigf(vf) * cv[j] + sigf(vi) * tanhf(vg);
      hv.h[j] = (f16)(sigf(vo) * tanhf(cv[j]));
    }
    __hip_atomic_store(&hout[(g * RG + row) * 256 + cg * 8 + (tid & 7)], hv.u,
                       __ATOMIC_RELAXED, __HIP_MEMORY_SCOPE_AGENT);
  }
}

__launch_bounds__(NTHREADS, 1)
__global__ void lstm_all(const int* __restrict__ xTok, const float* __restrict__ emb,
    const float* __restrict__ eWih0, const float* __restrict__ eWhh0,
    const float* __restrict__ ebih0, const float* __restrict__ ebhh0,
    const float* __restrict__ eWih1, const float* __restrict__ eWhh1,
    const float* __restrict__ ebih1, const float* __restrict__ ebhh1,
    const float* __restrict__ dWih0, const float* __restrict__ dWhh0,
    const float* __restrict__ dbih0, const float* __restrict__ dbhh0,
    const float* __restrict__ dWih1, const float* __restrict__ dWhh1,
    const float* __restrict__ dbih1, const float* __restrict__ dbhh1,
    const float* __restrict__ fcw, const float* __restrict__ fcb,
    float* __restrict__ dout, char* __restrict__ h0buf, char* __restrict__ h1buf,
    int* __restrict__ slots)
{
  __shared__ __align__(16) char upool[RG * XSTR * 2];  // enc: xe stage | dec: lbuf + w0d
  __shared__ __align__(16) f16 h0s[RG * HSTR];
  __shared__ __align__(16) f16 h1s[RG * HSTR];
  __shared__ float gbuf[RG * GSTR];
  __shared__ int amaxlds[RG];
  __shared__ int esc;

  f16*   xes  = (f16*)upool;
  float* lbuf = (float*)upool;            // [RG][33] logits (decoder only)
  float* w0d  = (float*)(upool + 4352);   // [64][32] dec_Wih0 slice (decoder only)

  const int tid  = threadIdx.x;
  const int g    = blockIdx.x & 7;        // batch group (R2-proven mapping)
  const int cg   = blockIdx.x >> 3;       // col-group within group, 0..31
  const int w    = tid >> 6;              // wave = gate index 0..3
  const int lane = tid & 63;
  const int quad = lane >> 4;
  const int l16  = lane & 15;
  const int colg = w * HN + cg * 16 + l16;  // global gate column (2048-space)
  int epoch = 0;
  if (tid == 0) esc = 0;

  // ---- encoder weights -> VGPR B-fragments
  f16x8 Wi0r[8], Wh0r[16], Wi1r[16], Wh1r[16];
  loadW<8>(eWih0, EN, colg, quad, Wi0r);
  loadW<16>(eWhh0, HN, colg, quad, Wh0r);
  loadW<16>(eWih1, HN, colg, quad, Wi1r);
  loadW<16>(eWhh1, HN, colg, quad, Wh1r);
  float bias0 = ebih0[colg] + ebhh0[colg];
  float bias1 = ebih1[colg] + ebhh1[colg];

  // ---- xe(0) pre-gather; zero h(-1) (parity 1); zero cell state
  gatherXE(xes, xTok, emb, g, 0, tid);
  float c0[2] = {0.f, 0.f}, c1[2] = {0.f, 0.f};
  {
    int row = tid >> 3, sub = tid & 7;
    unsigned idx = (unsigned)(BN * 256 + (g * RG + row) * 256 + cg * 8 + sub);
    __hip_atomic_store((unsigned*)h0buf + idx, 0u, __ATOMIC_RELAXED, __HIP_MEMORY_SCOPE_AGENT);
    __hip_atomic_store((unsigned*)h1buf + idx, 0u, __ATOMIC_RELAXED, __HIP_MEMORY_SCOPE_AGENT);
  }
  ++epoch; barrier_arrive(slots, g, cg, tid, epoch); barrier_wait(slots, g, tid, epoch, &esc);

  // ================= encoder: wavefront, interval k does cell0@k + cell1@(k-1)
  for (int k = 0; k <= SN; ++k) {
    const char* h0src = h0buf + (size_t)((k - 1) & 1) * BN * HN * 2 + (size_t)(g * RG) * HN * 2;
    if (k >= 1)
      stage2(h0s, h0src,
             h1s, h1buf + (size_t)(k & 1) * BN * HN * 2 + (size_t)(g * RG) * HN * 2, tid);
    else
      stage1(h0s, h0src, tid);
    __syncthreads();

    f32x4 acc0[2], acc1[2];
    if (k < SN) {   // cell0@k : xe@Wih0^T + h0@Whh0^T + b
      f32x4 b0; b0[0] = bias0; b0[1] = bias0; b0[2] = bias0; b0[3] = bias0;
      acc0[0] = b0; acc0[1] = b0;
      matmulAcc<8>(acc0, xes, XSTR, Wi0r, l16, quad);
      matmulAcc<16>(acc0, h0s, HSTR, Wh0r, l16, quad);
    }
    if (k >= 1) {   // cell1@(k-1) : h0@(k-1)@Wih1^T + h1@(k-2)@Whh1^T + b
      f32x4 b1; b1[0] = bias1; b1[1] = bias1; b1[2] = bias1; b1[3] = bias1;
      acc1[0] = b1; acc1[1] = b1;
      matmulAcc<16>(acc1, h0s, HSTR, Wi1r, l16, quad);
      matmulAcc<16>(acc1, h1s, HSTR, Wh1r, l16, quad);
    }
    if (k < SN)
      exchUpdate(acc0, gbuf, w, quad, l16, tid, c0,
                 (unsigned*)(h0buf + (size_t)(k & 1) * BN * HN * 2), g, cg);
    if (k >= 1) {
      __syncthreads();  // gbuf reuse guard
      exchUpdate(acc1, gbuf, w, quad, l16, tid, c1,
                 (unsigned*)(h1buf + (size_t)((k - 1) & 1) * BN * HN * 2), g, cg);
    }
    ++epoch;
    barrier_arrive(slots, g, cg, tid, epoch);
    if (k < SN - 1) gatherXE(xes, xTok, emb, g, k + 1, tid);   // hidden in the gap
    barrier_wait(slots, g, tid, epoch, &esc);
  }

  // ================= decoder setup: swap weight regs to decoder weights
  loadW<16>(dWhh0, HN, colg, quad, Wh0r);
  loadW<16>(dWih1, HN, colg, quad, Wi1r);
  loadW<16>(dWhh1, HN, colg, quad, Wh1r);
  bias0 = dbih0[colg] + dbhh0[colg];
  bias1 = dbih1[colg] + dbhh1[colg];
  {   // dec_Wih0 slice [64 owned cols][32 inputs] -> LDS (one-hot gather table)
    int cl = tid >> 2, i0 = (tid & 3) * 8;
    int gcol = (cl >> 4) * HN + cg * 16 + (cl & 15);
    const float* p = dWih0 + (size_t)gcol * ON + i0;
    #pragma unroll
    for (int j = 0; j < 8; ++j) w0d[cl * 32 + i0 + j] = p[j];
  }
  if (tid < RG) amaxlds[tid] = 0;   // xin(0) = one-hot(0)
  // note: h0s still holds h0@127 (staged at k=128); h1buf parity1 = h1@127.
  // cell states c0,c1 carry over from encoder finals (reference semantics).

  // ================= decoder: I1 = [fc+softmax+amax@(t-1)] + cell0@t ; I2 = cell1@t
  for (int t = 0; t <= SN; ++t) {
    stage1(h1s, h1buf + (size_t)((t - 1) & 1) * BN * HN * 2 + (size_t)(g * RG) * HN * 2, tid);
    __syncthreads();

    if (t >= 1) {
      int st = t - 1;
      int fmt = w & 1, fnt = w >> 1;
      int colo = fnt * 16 + l16;
      f32x4 afc;
      { float fb = fcb[st * ON + colo]; afc[0] = fb; afc[1] = fb; afc[2] = fb; afc[3] = fb; }
      #pragma unroll
      for (int kt = 0; kt < 16; ++kt) {   // B-frag from fp32 fc_w (cached), inline cvt
        const float* p = fcw + ((size_t)st * ON + colo) * HN + kt * 32 + quad * 8;
        f32x4 a = *(const f32x4*)p;
        f32x4 b = *(const f32x4*)(p + 4);
        f16x8 bf;
        bf[0] = (f16)a[0]; bf[1] = (f16)a[1]; bf[2] = (f16)a[2]; bf[3] = (f16)a[3];
        bf[4] = (f16)b[0]; bf[5] = (f16)b[1]; bf[6] = (f16)b[2]; bf[7] = (f16)b[3];
        f16x8 av = *(const f16x8*)&h1s[(fmt * 16 + l16) * HSTR + kt * 32 + quad * 8];
        afc = MFMA16(av, bf, afc);
      }
      #pragma unroll
      for (int i = 0; i < 4; ++i)
        lbuf[(fmt * 16 + quad * 4 + i) * 33 + colo] = afc[i];
      __syncthreads();
      if (tid < RG) {   // per-row softmax + argmax (first-max semantics)
        float mx = lbuf[tid * 33]; int bi = 0;
        #pragma unroll
        for (int c = 1; c < ON; ++c) { float v = lbuf[tid * 33 + c]; if (v > mx) { mx = v; bi = c; } }
        float ss = 0.f;
        #pragma unroll
        for (int c = 0; c < ON; ++c) ss += __expf(lbuf[tid * 33 + c] - mx);
        amaxlds[tid] = bi;
        if (cg == 0) {
          float inv = 1.0f / ss;
          float* op = dout + ((size_t)(g * RG + tid) * SN + st) * ON;
          #pragma unroll
          for (int c = 0; c < ON; ++c) op[c] = __expf(lbuf[tid * 33 + c] - mx) * inv;
        }
      }
      __syncthreads();
    }

    if (t < SN) {   // cell0@t : gather(dec_Wih0, amax) + h0@(t-1)@Whh0^T + b
      f32x4 acc0[2];
      #pragma unroll
      for (int mt = 0; mt < 2; ++mt) {
        #pragma unroll
        for (int i = 0; i < 4; ++i) {
          int row = mt * 16 + quad * 4 + i;
          acc0[mt][i] = bias0 + w0d[(w * 16 + l16) * 32 + amaxlds[row]];
        }
      }
      matmulAcc<16>(acc0, h0s, HSTR, Wh0r, l16, quad);
      exchUpdate(acc0, gbuf, w, quad, l16, tid, c0,
                 (unsigned*)(h0buf + (size_t)(t & 1) * BN * HN * 2), g, cg);
    }
    ++epoch; barrier_arrive(slots, g, cg, tid, epoch); barrier_wait(slots, g, tid, epoch, &esc);

    if (t < SN) {   // I2: cell1@t : h0@t@Wih1^T + h1@(t-1)@Whh1^T + b
      stage1(h0s, h0buf + (size_t)(t & 1) * BN * HN * 2 + (size_t)(g * RG) * HN * 2, tid);
      __syncthreads();
      f32x4 acc1[2];
      f32x4 b1; b1[0] = bias1; b1[1] = bias1; b1[2] = bias1; b1[3] = bias1;
      acc1[0] = b1; acc1[1] = b1;
      matmulAcc<16>(acc1, h0s, HSTR, Wi1r, l16, quad);
      matmulAcc<16>(acc1, h1s, HSTR, Wh1r, l16, quad);
      exchUpdate(acc1, gbuf, w, quad, l16, tid, c1,
                 (unsigned*)(h1buf + (size_t)(t & 1) * BN * HN * 2), g, cg);
      ++epoch; barrier_arrive(slots, g, cg, tid, epoch); barrier_wait(slots, g, tid, epoch, &esc);
    }
  }
}

extern "C" void kernel_launch(void* const* d_in, const int* in_sizes, int n_in,
                              void* d_out, int out_size, void* d_ws, size_t ws_size,
                              hipStream_t stream) {
  (void)in_sizes; (void)n_in; (void)out_size; (void)ws_size;
  const int*   xTok  = (const int*)d_in[0];
  const float* emb   = (const float*)d_in[1];
  const float* eWih0 = (const float*)d_in[2];
  const float* eWhh0 = (const float*)d_in[3];
  const float* ebih0 = (const float*)d_in[4];
  const float* ebhh0 = (const float*)d_in[5];
  const float* eWih1 = (const float*)d_in[6];
  const float* eWhh1 = (const float*)d_in[7];
  const float* ebih1 = (const float*)d_in[8];
  const float* ebhh1 = (const float*)d_in[9];
  const float* dWih0 = (const float*)d_in[10];
  const float* dWhh0 = (const float*)d_in[11];
  const float* dbih0 = (const float*)d_in[12];
  const float* dbhh0 = (const float*)d_in[13];
  const float* dWih1 = (const float*)d_in[14];
  const float* dWhh1 = (const float*)d_in[15];
  const float* dbih1 = (const float*)d_in[16];
  const float* dbhh1 = (const float*)d_in[17];
  const float* fcw   = (const float*)d_in[18];
  const float* fcb   = (const float*)d_in[19];

  // ws layout (R1/R2-proven footprint): h0buf [2][256][512] f16 (512KB) |
  // h1buf (512KB) | slots [8][64] int (2KB, flags 0..31 per group)
  char* h0buf = (char*)d_ws;
  char* h1buf = (char*)d_ws + (size_t)2 * BN * HN * 2;
  int*  slots = (int*)((char*)d_ws + (size_t)4 * BN * HN * 2);

  hipLaunchKernelGGL(lstm_all, dim3(256), dim3(NTHREADS), 0, stream,
                     xTok, emb, eWih0, eWhh0, ebih0, ebhh0, eWih1, eWhh1, ebih1, ebhh1,
                     dWih0, dWhh0, dbih0, dbhh0, dWih1, dWhh1, dbih1, dbhh1,
                     fcw, fcb, (float*)d_out, h0buf, h1buf, slots);
}

// Round 6
// 3006.070 us; speedup vs baseline: 1.9520x; 1.0164x over previous
//
#include <hip/hip_runtime.h>

// ---------------------------------------------------------------------------
// NER LSTM (B=256,S=128,E=256,H=512,O=32) — one persistent kernel.
// 256 wgs x 256 threads, 1 block/CU. 8 batch groups (32 rows) x 32 col-group
// wgs (g=blockIdx&7). Recurrent weights in VGPRs/AGPRs as f16 MFMA B-frags.
// Transport = R5-proven sc1/MALL (relaxed agent atomics for stores/flags,
// batched global_load_dwordx4 sc1 for stage reads).
// R6 vs R5 (latency hiding, transport unchanged):
//  1. Stage loads overlapped with independent MFMAs using in-order-retire
//     vmcnt(8)/vmcnt(0) splits (stage RT was fully exposed in R5).
//  2. Parallel softmax/argmax: 8 threads/row + shfl_xor (was 32-thread serial).
//  3. Encoder: both cells' exchanges merged (one sync + one pointwise pass).
//  4. All-wave barrier polling; emb gather in arrive->poll gap + local sync.
// ---------------------------------------------------------------------------

#define BN 256
#define SN 128
#define EN 256
#define HN 512
#define ON 32
#define RG 32          // batch rows per group
#define NCG 32         // col-group wgs per group
#define NTHREADS 256
#define XSTR 264       // xe stage row stride (f16): 256 + 8 pad
#define HSTR 520       // h  stage row stride (f16): 512 + 8 pad
#define GSTR 68        // gbuf row stride (floats): 64 + 4 pad
#define POLL_GUARD (1 << 20)

typedef _Float16 f16;
typedef _Float16 f16x8 __attribute__((ext_vector_type(8)));
typedef _Float16 f16x2 __attribute__((ext_vector_type(2)));
typedef float f32x4 __attribute__((ext_vector_type(4)));
typedef unsigned u32x4 __attribute__((ext_vector_type(4)));

__device__ __forceinline__ f32x4 MFMA16(f16x8 a, f16x8 b, f32x4 c) {
  return __builtin_amdgcn_mfma_f32_16x16x32_f16(a, b, c, 0, 0, 0);
}

__device__ __forceinline__ float sigf(float x) { return 1.0f / (1.0f + __expf(-x)); }

// Load B-fragment slice of W [4H x K] (row-major) for column `col`:
// lane holds W[col][kt*32 + quad*8 + j], j=0..7.
template<int NKT>
__device__ __forceinline__ void loadW(const float* __restrict__ Wb, int K, int col, int quad,
                                      f16x8* dst) {
  #pragma unroll
  for (int kt = 0; kt < NKT; ++kt) {
    const float* p = Wb + (size_t)col * K + kt * 32 + quad * 8;
    f32x4 a = *(const f32x4*)p;
    f32x4 b = *(const f32x4*)(p + 4);
    f16x8 h;
    h[0] = (f16)a[0]; h[1] = (f16)a[1]; h[2] = (f16)a[2]; h[3] = (f16)a[3];
    h[4] = (f16)b[0]; h[5] = (f16)b[1]; h[6] = (f16)b[2]; h[7] = (f16)b[3];
    dst[kt] = h;
  }
}

// Issue 8 batched dwordx4 sc1 loads for one [RG x HN] f16 tile (32KB).
__device__ __forceinline__ void issue8(u32x4* v, const char* __restrict__ src, int tid) {
  const char* base = src + tid * 16;
  #pragma unroll
  for (int j = 0; j < 8; ++j)
    asm volatile("global_load_dwordx4 %0, %1, off sc1" : "=v"(v[j]) : "v"(base + j * 4096));
}
// Scatter the 8 loaded vectors into padded LDS (call after the waitcnt).
__device__ __forceinline__ void write8(f16* dst, const u32x4* v, int tid) {
  #pragma unroll
  for (int j = 0; j < 8; ++j) {
    int u = j * 256 + tid, rr = u >> 6, cc = u & 63;
    *(u32x4*)&dst[rr * HSTR + cc * 8] = v[j];
  }
}

// acc[mt] += stage(rows mt*16..) x Wr   (A[m=lane&15][k=quad*8+j] layout)
template<int NKT>
__device__ __forceinline__ void matmulAcc(f32x4* acc, const f16* stage, int stride,
                                          const f16x8* Wr, int l16, int quad) {
  #pragma unroll
  for (int mt = 0; mt < 2; ++mt) {
    #pragma unroll
    for (int kt = 0; kt < NKT; ++kt) {
      f16x8 a = *(const f16x8*)&stage[(mt * 16 + l16) * stride + kt * 32 + quad * 8];
      acc[mt] = MFMA16(a, Wr[kt], acc[mt]);
    }
  }
}

// Barrier arrive: leading __syncthreads carries each wave's vmcnt(0) drain,
// so all sc1 h-stores are MALL-visible before the flag store.
__device__ __forceinline__ void barrier_arrive(int* slots, int g, int cg, int tid, int epoch) {
  __syncthreads();
  if (tid == 0) {
    asm volatile("s_waitcnt vmcnt(0)" ::: "memory");
    __hip_atomic_store(&slots[g * 64 + cg], epoch, __ATOMIC_RELAXED, __HIP_MEMORY_SCOPE_AGENT);
  }
}

// Barrier wait: ALL waves poll the group's 32 flags (relaxed agent atomics);
// each wave proceeds on its own observation (flags are monotone; all LDS the
// wave touches next is dead after the arrive-sync). Escape guard latches.
__device__ __forceinline__ void barrier_wait(int* slots, int g, int tid, int epoch, int* esc) {
  if (!*esc) {
    int idx = tid & 31;
    int gd = 0;
    for (;;) {
      int v = __hip_atomic_load(&slots[g * 64 + idx], __ATOMIC_RELAXED, __HIP_MEMORY_SCOPE_AGENT);
      if (__all(v >= epoch)) break;
      if (++gd > POLL_GUARD) { *esc = 1; break; }
      __builtin_amdgcn_s_sleep(1);
    }
  }
  asm volatile("" ::: "memory");
}

// Gather one time-step of embeddings for the group's 32 rows -> xes (f16).
__device__ __forceinline__ void gatherXE(f16* xes, const int* __restrict__ xTok,
                                         const float* __restrict__ emb, int g, int k, int tid) {
  int r = tid >> 3, sub = tid & 7;
  int tok = xTok[(g * RG + r) * SN + k];
  const float* er = emb + (size_t)tok * EN + sub * 32;
  f16* dst = &xes[r * XSTR + sub * 32];
  #pragma unroll
  for (int jj = 0; jj < 32; jj += 8) {
    f32x4 a = *(const f32x4*)(er + jj);
    f32x4 b = *(const f32x4*)(er + jj + 4);
    f16x8 hv;
    hv[0] = (f16)a[0]; hv[1] = (f16)a[1]; hv[2] = (f16)a[2]; hv[3] = (f16)a[3];
    hv[4] = (f16)b[0]; hv[5] = (f16)b[1]; hv[6] = (f16)b[2]; hv[7] = (f16)b[3];
    *(f16x8*)(dst + jj) = hv;
  }
}

// fp32 LSTM pointwise for one cell from a gate buffer + packed f16x2 sc1 store.
__device__ __forceinline__ void pointwise_store(const float* gb, int row, int d0, float* cv,
                                                unsigned* __restrict__ hout, int g, int cg,
                                                int sub) {
  const float* gr = gb + row * GSTR + d0;
  union { unsigned u; f16x2 h; } hv;
  #pragma unroll
  for (int j = 0; j < 2; ++j) {
    float vi = gr[j], vf = gr[16 + j], vg = gr[32 + j], vo = gr[48 + j];
    cv[j] = sigf(vf) * cv[j] + sigf(vi) * tanhf(vg);
    hv.h[j] = (f16)(sigf(vo) * tanhf(cv[j]));
  }
  __hip_atomic_store(&hout[(g * RG + row) * 256 + cg * 8 + sub], hv.u,
                     __ATOMIC_RELAXED, __HIP_MEMORY_SCOPE_AGENT);
}

__launch_bounds__(NTHREADS, 1)
__global__ void lstm_all(const int* __restrict__ xTok, const float* __restrict__ emb,
    const float* __restrict__ eWih0, const float* __restrict__ eWhh0,
    const float* __restrict__ ebih0, const float* __restrict__ ebhh0,
    const float* __restrict__ eWih1, const float* __restrict__ eWhh1,
    const float* __restrict__ ebih1, const float* __restrict__ ebhh1,
    const float* __restrict__ dWih0, const float* __restrict__ dWhh0,
    const float* __restrict__ dbih0, const float* __restrict__ dbhh0,
    const float* __restrict__ dWih1, const float* __restrict__ dWhh1,
    const float* __restrict__ dbih1, const float* __restrict__ dbhh1,
    const float* __restrict__ fcw, const float* __restrict__ fcb,
    float* __restrict__ dout, char* __restrict__ h0buf, char* __restrict__ h1buf,
    int* __restrict__ slots)
{
  __shared__ __align__(16) char upool[RG * XSTR * 2];  // enc: xe stage | dec: lbuf + w0d
  __shared__ __align__(16) f16 h0s[RG * HSTR];
  __shared__ __align__(16) f16 h1s[RG * HSTR];
  __shared__ float gbuf0[RG * GSTR];
  __shared__ float gbuf1[RG * GSTR];
  __shared__ int amaxlds[RG];
  __shared__ int esc;

  f16*   xes  = (f16*)upool;
  float* lbuf = (float*)upool;            // [RG][33] logits (decoder only)
  float* w0d  = (float*)(upool + 4352);   // [64][32] dec_Wih0 slice (decoder only)

  const int tid  = threadIdx.x;
  const int g    = blockIdx.x & 7;        // batch group
  const int cg   = blockIdx.x >> 3;       // col-group within group, 0..31
  const int w    = tid >> 6;              // wave = gate index 0..3
  const int lane = tid & 63;
  const int quad = lane >> 4;
  const int l16  = lane & 15;
  const int colg = w * HN + cg * 16 + l16;  // global gate column (2048-space)
  const int urow = tid >> 3;              // pointwise: row 0..31
  const int ud0  = (tid & 7) * 2;         // pointwise: dim pair base
  int epoch = 0;
  if (tid == 0) esc = 0;

  // ---- encoder weights -> register B-fragments
  f16x8 Wi0r[8], Wh0r[16], Wi1r[16], Wh1r[16];
  loadW<8>(eWih0, EN, colg, quad, Wi0r);
  loadW<16>(eWhh0, HN, colg, quad, Wh0r);
  loadW<16>(eWih1, HN, colg, quad, Wi1r);
  loadW<16>(eWhh1, HN, colg, quad, Wh1r);
  float bias0 = ebih0[colg] + ebhh0[colg];
  float bias1 = ebih1[colg] + ebhh1[colg];

  // ---- xe(0) pre-gather; zero h(-1) (parity 1); zero cell state
  gatherXE(xes, xTok, emb, g, 0, tid);
  float c0[2] = {0.f, 0.f}, c1[2] = {0.f, 0.f};
  {
    unsigned idx = (unsigned)(BN * 256 + (g * RG + urow) * 256 + cg * 8 + (tid & 7));
    __hip_atomic_store((unsigned*)h0buf + idx, 0u, __ATOMIC_RELAXED, __HIP_MEMORY_SCOPE_AGENT);
    __hip_atomic_store((unsigned*)h1buf + idx, 0u, __ATOMIC_RELAXED, __HIP_MEMORY_SCOPE_AGENT);
  }
  ++epoch; barrier_arrive(slots, g, cg, tid, epoch);
  __syncthreads();
  barrier_wait(slots, g, tid, epoch, &esc);

  // ================= encoder: interval k does cell0@k + cell1@(k-1)
  for (int k = 0; k <= SN; ++k) {
    u32x4 v0[8], v1[8];
    issue8(v0, h0buf + (size_t)((k - 1) & 1) * BN * HN * 2 + (size_t)(g * RG) * HN * 2, tid);
    if (k >= 1)
      issue8(v1, h1buf + (size_t)(k & 1) * BN * HN * 2 + (size_t)(g * RG) * HN * 2, tid);

    f32x4 acc0[2], acc1[2];
    if (k < SN) {   // xe part of cell0 overlaps the stage loads
      f32x4 b0; b0[0] = bias0; b0[1] = bias0; b0[2] = bias0; b0[3] = bias0;
      acc0[0] = b0; acc0[1] = b0;
      matmulAcc<8>(acc0, xes, XSTR, Wi0r, l16, quad);
    }
    if (k >= 1) asm volatile("s_waitcnt vmcnt(8)" ::: "memory");  // h0 batch retired
    else        asm volatile("s_waitcnt vmcnt(0)" ::: "memory");
    write8(h0s, v0, tid);
    __syncthreads();
    if (k < SN) matmulAcc<16>(acc0, h0s, HSTR, Wh0r, l16, quad);   // h1 still in flight
    if (k >= 1) {
      f32x4 b1; b1[0] = bias1; b1[1] = bias1; b1[2] = bias1; b1[3] = bias1;
      acc1[0] = b1; acc1[1] = b1;
      matmulAcc<16>(acc1, h0s, HSTR, Wi1r, l16, quad);
      asm volatile("s_waitcnt vmcnt(0)" ::: "memory");
      write8(h1s, v1, tid);
      __syncthreads();
      matmulAcc<16>(acc1, h1s, HSTR, Wh1r, l16, quad);
    }

    // merged exchange: both cells, one sync, one pointwise pass
    #pragma unroll
    for (int mt = 0; mt < 2; ++mt) {
      #pragma unroll
      for (int i = 0; i < 4; ++i) {
        int rr = (mt * 16 + quad * 4 + i) * GSTR + w * 16 + l16;
        if (k < SN) gbuf0[rr] = acc0[mt][i];
        if (k >= 1) gbuf1[rr] = acc1[mt][i];
      }
    }
    __syncthreads();
    if (k < SN)
      pointwise_store(gbuf0, urow, ud0, c0,
                      (unsigned*)(h0buf + (size_t)(k & 1) * BN * HN * 2), g, cg, tid & 7);
    if (k >= 1)
      pointwise_store(gbuf1, urow, ud0, c1,
                      (unsigned*)(h1buf + (size_t)((k - 1) & 1) * BN * HN * 2), g, cg, tid & 7);

    ++epoch;
    barrier_arrive(slots, g, cg, tid, epoch);
    if (k < SN - 1) gatherXE(xes, xTok, emb, g, k + 1, tid);   // hidden in the gap
    __syncthreads();   // gather-complete guard (all-wave poll exits independently)
    barrier_wait(slots, g, tid, epoch, &esc);
  }

  // ================= decoder setup: swap weight regs to decoder weights
  loadW<16>(dWhh0, HN, colg, quad, Wh0r);
  loadW<16>(dWih1, HN, colg, quad, Wi1r);
  loadW<16>(dWhh1, HN, colg, quad, Wh1r);
  bias0 = dbih0[colg] + dbhh0[colg];
  bias1 = dbih1[colg] + dbhh1[colg];
  {   // dec_Wih0 slice [64 owned cols][32 inputs] -> LDS (one-hot gather table)
    int cl = tid >> 2, i0 = (tid & 3) * 8;
    int gcol = (cl >> 4) * HN + cg * 16 + (cl & 15);
    const float* p = dWih0 + (size_t)gcol * ON + i0;
    #pragma unroll
    for (int j = 0; j < 8; ++j) w0d[cl * 32 + i0 + j] = p[j];
  }
  if (tid < RG) amaxlds[tid] = 0;   // xin(0) = one-hot(0)
  // h0s holds h0@127 (staged at k=128); h1buf parity1 = h1@127; c0,c1 carry.

  // ================= decoder: I1 = [fc+softmax+amax@(t-1)] + cell0@t ; I2 = cell1@t
  for (int t = 0; t <= SN; ++t) {
    u32x4 v0[8];
    issue8(v0, h1buf + (size_t)((t - 1) & 1) * BN * HN * 2 + (size_t)(g * RG) * HN * 2, tid);

    f32x4 acc0[2];
    if (t < SN) {   // Whh0 part of cell0 (h0s ready) overlaps the h1 stage
      acc0[0] = f32x4{0.f, 0.f, 0.f, 0.f}; acc0[1] = acc0[0];
      matmulAcc<16>(acc0, h0s, HSTR, Wh0r, l16, quad);
    }
    asm volatile("s_waitcnt vmcnt(0)" ::: "memory");
    write8(h1s, v0, tid);
    __syncthreads();

    if (t >= 1) {
      int st = t - 1;
      int fmt = w & 1, fnt = w >> 1;
      int colo = fnt * 16 + l16;
      f32x4 afc;
      { float fb = fcb[st * ON + colo]; afc[0] = fb; afc[1] = fb; afc[2] = fb; afc[3] = fb; }
      #pragma unroll
      for (int kt = 0; kt < 16; ++kt) {   // B-frag from fp32 fc_w (cached), inline cvt
        const float* p = fcw + ((size_t)st * ON + colo) * HN + kt * 32 + quad * 8;
        f32x4 a = *(const f32x4*)p;
        f32x4 b = *(const f32x4*)(p + 4);
        f16x8 bf;
        bf[0] = (f16)a[0]; bf[1] = (f16)a[1]; bf[2] = (f16)a[2]; bf[3] = (f16)a[3];
        bf[4] = (f16)b[0]; bf[5] = (f16)b[1]; bf[6] = (f16)b[2]; bf[7] = (f16)b[3];
        f16x8 av = *(const f16x8*)&h1s[(fmt * 16 + l16) * HSTR + kt * 32 + quad * 8];
        afc = MFMA16(av, bf, afc);
      }
      #pragma unroll
      for (int i = 0; i < 4; ++i)
        lbuf[(fmt * 16 + quad * 4 + i) * 33 + colo] = afc[i];
      __syncthreads();
      {   // parallel softmax + argmax: 8 threads per row, shfl_xor reductions
        int row = tid >> 3, s = tid & 7, cbase = s * 4;
        float vv[4];
        #pragma unroll
        for (int j = 0; j < 4; ++j) vv[j] = lbuf[row * 33 + cbase + j];
        float mx = vv[0]; int bi = cbase;
        #pragma unroll
        for (int j = 1; j < 4; ++j)
          if (vv[j] > mx) { mx = vv[j]; bi = cbase + j; }
        #pragma unroll
        for (int m = 1; m < 8; m <<= 1) {
          float om = __shfl_xor(mx, m);
          int   ob = __shfl_xor(bi, m);
          if (om > mx || (om == mx && ob < bi)) { mx = om; bi = ob; }
        }
        float e[4], ss = 0.f;
        #pragma unroll
        for (int j = 0; j < 4; ++j) { e[j] = __expf(vv[j] - mx); ss += e[j]; }
        #pragma unroll
        for (int m = 1; m < 8; m <<= 1) ss += __shfl_xor(ss, m);
        if (s == 0) amaxlds[row] = bi;
        if (cg == 0) {
          float inv = 1.0f / ss;
          float* op = dout + ((size_t)(g * RG + row) * SN + st) * ON + cbase;
          #pragma unroll
          for (int j = 0; j < 4; ++j) op[j] = e[j] * inv;
        }
      }
      __syncthreads();
    }

    if (t < SN) {   // add bias + one-hot gather(dec_Wih0, amax), then exchange
      #pragma unroll
      for (int mt = 0; mt < 2; ++mt) {
        #pragma unroll
        for (int i = 0; i < 4; ++i) {
          int row = mt * 16 + quad * 4 + i;
          acc0[mt][i] += bias0 + w0d[(w * 16 + l16) * 32 + amaxlds[row]];
        }
      }
      #pragma unroll
      for (int mt = 0; mt < 2; ++mt) {
        #pragma unroll
        for (int i = 0; i < 4; ++i)
          gbuf0[(mt * 16 + quad * 4 + i) * GSTR + w * 16 + l16] = acc0[mt][i];
      }
      __syncthreads();
      pointwise_store(gbuf0, urow, ud0, c0,
                      (unsigned*)(h0buf + (size_t)(t & 1) * BN * HN * 2), g, cg, tid & 7);
    }
    ++epoch; barrier_arrive(slots, g, cg, tid, epoch); barrier_wait(slots, g, tid, epoch, &esc);

    if (t < SN) {   // I2: cell1@t : h0@t@Wih1^T + h1@(t-1)@Whh1^T + b
      u32x4 v2[8];
      issue8(v2, h0buf + (size_t)(t & 1) * BN * HN * 2 + (size_t)(g * RG) * HN * 2, tid);
      f32x4 acc1[2];
      f32x4 b1; b1[0] = bias1; b1[1] = bias1; b1[2] = bias1; b1[3] = bias1;
      acc1[0] = b1; acc1[1] = b1;
      matmulAcc<16>(acc1, h1s, HSTR, Wh1r, l16, quad);   // h1@(t-1), overlaps stage
      asm volatile("s_waitcnt vmcnt(0)" ::: "memory");
      write8(h0s, v2, tid);
      __syncthreads();
      matmulAcc<16>(acc1, h0s, HSTR, Wi1r, l16, quad);
      #pragma unroll
      for (int mt = 0; mt < 2; ++mt) {
        #pragma unroll
        for (int i = 0; i < 4; ++i)
          gbuf0[(mt * 16 + quad * 4 + i) * GSTR + w * 16 + l16] = acc1[mt][i];
      }
      __syncthreads();
      pointwise_store(gbuf0, urow, ud0, c1,
                      (unsigned*)(h1buf + (size_t)(t & 1) * BN * HN * 2), g, cg, tid & 7);
      ++epoch; barrier_arrive(slots, g, cg, tid, epoch); barrier_wait(slots, g, tid, epoch, &esc);
    }
  }
}

extern "C" void kernel_launch(void* const* d_in, const int* in_sizes, int n_in,
                              void* d_out, int out_size, void* d_ws, size_t ws_size,
                              hipStream_t stream) {
  (void)in_sizes; (void)n_in; (void)out_size; (void)ws_size;
  const int*   xTok  = (const int*)d_in[0];
  const float* emb   = (const float*)d_in[1];
  const float* eWih0 = (const float*)d_in[2];
  const float* eWhh0 = (const float*)d_in[3];
  const float* ebih0 = (const float*)d_in[4];
  const float* ebhh0 = (const float*)d_in[5];
  const float* eWih1 = (const float*)d_in[6];
  const float* eWhh1 = (const float*)d_in[7];
  const float* ebih1 = (const float*)d_in[8];
  const float* ebhh1 = (const float*)d_in[9];
  const float* dWih0 = (const float*)d_in[10];
  const float* dWhh0 = (const float*)d_in[11];
  const float* dbih0 = (const float*)d_in[12];
  const float* dbhh0 = (const float*)d_in[13];
  const float* dWih1 = (const float*)d_in[14];
  const float* dWhh1 = (const float*)d_in[15];
  const float* dbih1 = (const float*)d_in[16];
  const float* dbhh1 = (const float*)d_in[17];
  const float* fcw   = (const float*)d_in[18];
  const float* fcb   = (const float*)d_in[19];

  // ws layout (proven footprint): h0buf [2][256][512] f16 (512KB) |
  // h1buf (512KB) | slots [8][64] int (2KB, flags 0..31 per group)
  char* h0buf = (char*)d_ws;
  char* h1buf = (char*)d_ws + (size_t)2 * BN * HN * 2;
  int*  slots = (int*)((char*)d_ws + (size_t)4 * BN * HN * 2);

  hipLaunchKernelGGL(lstm_all, dim3(256), dim3(NTHREADS), 0, stream,
                     xTok, emb, eWih0, eWhh0, ebih0, ebhh0, eWih1, eWhh1, ebih1, ebhh1,
                     dWih0, dWhh0, dbih0, dbhh0, dWih1, dWhh1, dbih1, dbhh1,
                     fcw, fcb, (float*)d_out, h0buf, h1buf, slots);
}

// Round 7
// 2412.717 us; speedup vs baseline: 2.4320x; 1.2459x over previous
//
#include <hip/hip_runtime.h>

// ---------------------------------------------------------------------------
// NER LSTM (B=256,S=128,E=256,H=512,O=32) — one persistent kernel.
// 256 wgs x 256 threads, 1 block/CU. 8 batch groups (32 rows) x 32 col-group
// wgs (g=blockIdx&7). Recurrent weights in VGPRs as f16 MFMA B-frags.
// h transport = proven sc1/MALL (relaxed agent atomic stores, batched
// global_load_dwordx4 sc1 stage reads).
// R7 vs R6:
//  1. Counter barrier: arrive = ONE fire-and-forget global_atomic_add per wg
//     on a per-group counter; wait = poll a single dword (>= 32*n). Replaces
//     the 32-writer flag line + 32-lane ballot polling (line contention).
//     Init barrier stays flag-based (proven) and resets the counters.
//  2. fcw de-chained: fcw[st] staged fp32->f16 into LDS during I2's
//     arrive->wait gap (off the serial chain); I1's FC reads LDS B-frags.
//     Same RTE f32->f16 conversion => bit-identical logits and argmax.
// ---------------------------------------------------------------------------

#define BN 256
#define SN 128
#define EN 256
#define HN 512
#define ON 32
#define RG 32          // batch rows per group
#define NCG 32         // col-group wgs per group
#define NTHREADS 256
#define XSTR 264       // xe stage row stride (f16): 256 + 8 pad
#define HSTR 520       // h  stage row stride (f16): 512 + 8 pad
#define FSTR 520       // fcw stage row stride (f16): 512 + 8 pad
#define GSTR 68        // gbuf row stride (floats): 64 + 4 pad
#define POLL_GUARD (1 << 20)

typedef _Float16 f16;
typedef _Float16 f16x8 __attribute__((ext_vector_type(8)));
typedef _Float16 f16x2 __attribute__((ext_vector_type(2)));
typedef float f32x4 __attribute__((ext_vector_type(4)));
typedef unsigned u32x4 __attribute__((ext_vector_type(4)));

__device__ __forceinline__ f32x4 MFMA16(f16x8 a, f16x8 b, f32x4 c) {
  return __builtin_amdgcn_mfma_f32_16x16x32_f16(a, b, c, 0, 0, 0);
}

__device__ __forceinline__ float sigf(float x) { return 1.0f / (1.0f + __expf(-x)); }

// Load B-fragment slice of W [4H x K] (row-major) for column `col`:
// lane holds W[col][kt*32 + quad*8 + j], j=0..7.
template<int NKT>
__device__ __forceinline__ void loadW(const float* __restrict__ Wb, int K, int col, int quad,
                                      f16x8* dst) {
  #pragma unroll
  for (int kt = 0; kt < NKT; ++kt) {
    const float* p = Wb + (size_t)col * K + kt * 32 + quad * 8;
    f32x4 a = *(const f32x4*)p;
    f32x4 b = *(const f32x4*)(p + 4);
    f16x8 h;
    h[0] = (f16)a[0]; h[1] = (f16)a[1]; h[2] = (f16)a[2]; h[3] = (f16)a[3];
    h[4] = (f16)b[0]; h[5] = (f16)b[1]; h[6] = (f16)b[2]; h[7] = (f16)b[3];
    dst[kt] = h;
  }
}

// Issue 8 batched dwordx4 sc1 loads for one [RG x HN] f16 tile (32KB).
__device__ __forceinline__ void issue8(u32x4* v, const char* __restrict__ src, int tid) {
  const char* base = src + tid * 16;
  #pragma unroll
  for (int j = 0; j < 8; ++j)
    asm volatile("global_load_dwordx4 %0, %1, off sc1" : "=v"(v[j]) : "v"(base + j * 4096));
}
// Scatter the 8 loaded vectors into padded LDS (call after the waitcnt).
__device__ __forceinline__ void write8(f16* dst, const u32x4* v, int tid) {
  #pragma unroll
  for (int j = 0; j < 8; ++j) {
    int u = j * 256 + tid, rr = u >> 6, cc = u & 63;
    *(u32x4*)&dst[rr * HSTR + cc * 8] = v[j];
  }
}

// acc[mt] += stage(rows mt*16..) x Wr   (A[m=lane&15][k=quad*8+j] layout)
template<int NKT>
__device__ __forceinline__ void matmulAcc(f32x4* acc, const f16* stage, int stride,
                                          const f16x8* Wr, int l16, int quad) {
  #pragma unroll
  for (int mt = 0; mt < 2; ++mt) {
    #pragma unroll
    for (int kt = 0; kt < NKT; ++kt) {
      f16x8 a = *(const f16x8*)&stage[(mt * 16 + l16) * stride + kt * 32 + quad * 8];
      acc[mt] = MFMA16(a, Wr[kt], acc[mt]);
    }
  }
}

// Counter barrier arrive: leading __syncthreads carries each wave's vmcnt(0)
// drain (all sc1 h-stores MALL-visible), then one fire-and-forget atomic add.
__device__ __forceinline__ void arrive_ctr(int* slots, int g, int tid) {
  __syncthreads();
  if (tid == 0) {
    asm volatile("s_waitcnt vmcnt(0)" ::: "memory");
    int one = 1;
    int* p = &slots[g * 64 + 40];
    asm volatile("global_atomic_add %0, %1, off" :: "v"(p), "v"(one) : "memory");
  }
}

// Counter barrier wait: every wave polls ONE dword (monotone counter) until
// it reaches the cumulative target. Escape guard latches in LDS.
__device__ __forceinline__ void wait_ctr(int* slots, int g, int target, int* esc) {
  if (!*esc) {
    const int* p = &slots[g * 64 + 40];
    int gd = 0;
    for (;;) {
      int v = __hip_atomic_load(p, __ATOMIC_RELAXED, __HIP_MEMORY_SCOPE_AGENT);
      if (v >= target) break;
      if (++gd > POLL_GUARD) { *esc = 1; break; }
      __builtin_amdgcn_s_sleep(1);
    }
  }
  asm volatile("" ::: "memory");
}

// Gather one time-step of embeddings for the group's 32 rows -> xes (f16).
__device__ __forceinline__ void gatherXE(f16* xes, const int* __restrict__ xTok,
                                         const float* __restrict__ emb, int g, int k, int tid) {
  int r = tid >> 3, sub = tid & 7;
  int tok = xTok[(g * RG + r) * SN + k];
  const float* er = emb + (size_t)tok * EN + sub * 32;
  f16* dst = &xes[r * XSTR + sub * 32];
  #pragma unroll
  for (int jj = 0; jj < 32; jj += 8) {
    f32x4 a = *(const f32x4*)(er + jj);
    f32x4 b = *(const f32x4*)(er + jj + 4);
    f16x8 hv;
    hv[0] = (f16)a[0]; hv[1] = (f16)a[1]; hv[2] = (f16)a[2]; hv[3] = (f16)a[3];
    hv[4] = (f16)b[0]; hv[5] = (f16)b[1]; hv[6] = (f16)b[2]; hv[7] = (f16)b[3];
    *(f16x8*)(dst + jj) = hv;
  }
}

// Stage fcw[st] ([ON][HN] fp32) -> LDS f16 (same RTE cvt as the old inline
// path => bit-identical logits). col = tid>>3 (0..31), 64 k per thread.
__device__ __forceinline__ void stageFCW(f16* fcwb, const float* __restrict__ fcw,
                                         int st, int tid) {
  int col = tid >> 3, k0 = (tid & 7) * 64;
  const float* src = fcw + ((size_t)st * ON + col) * HN + k0;
  f16* dstp = &fcwb[col * FSTR + k0];
  #pragma unroll
  for (int jj = 0; jj < 64; jj += 8) {
    f32x4 a = *(const f32x4*)(src + jj);
    f32x4 b = *(const f32x4*)(src + jj + 4);
    f16x8 hv;
    hv[0] = (f16)a[0]; hv[1] = (f16)a[1]; hv[2] = (f16)a[2]; hv[3] = (f16)a[3];
    hv[4] = (f16)b[0]; hv[5] = (f16)b[1]; hv[6] = (f16)b[2]; hv[7] = (f16)b[3];
    *(f16x8*)(dstp + jj) = hv;
  }
}

// fp32 LSTM pointwise for one cell from a gate buffer + packed f16x2 sc1 store.
__device__ __forceinline__ void pointwise_store(const float* gb, int row, int d0, float* cv,
                                                unsigned* __restrict__ hout, int g, int cg,
                                                int sub) {
  const float* gr = gb + row * GSTR + d0;
  union { unsigned u; f16x2 h; } hv;
  #pragma unroll
  for (int j = 0; j < 2; ++j) {
    float vi = gr[j], vf = gr[16 + j], vg = gr[32 + j], vo = gr[48 + j];
    cv[j] = sigf(vf) * cv[j] + sigf(vi) * tanhf(vg);
    hv.h[j] = (f16)(sigf(vo) * tanhf(cv[j]));
  }
  __hip_atomic_store(&hout[(g * RG + row) * 256 + cg * 8 + sub], hv.u,
                     __ATOMIC_RELAXED, __HIP_MEMORY_SCOPE_AGENT);
}

__launch_bounds__(NTHREADS, 1)
__global__ void lstm_all(const int* __restrict__ xTok, const float* __restrict__ emb,
    const float* __restrict__ eWih0, const float* __restrict__ eWhh0,
    const float* __restrict__ ebih0, const float* __restrict__ ebhh0,
    const float* __restrict__ eWih1, const float* __restrict__ eWhh1,
    const float* __restrict__ ebih1, const float* __restrict__ ebhh1,
    const float* __restrict__ dWih0, const float* __restrict__ dWhh0,
    const float* __restrict__ dbih0, const float* __restrict__ dbhh0,
    const float* __restrict__ dWih1, const float* __restrict__ dWhh1,
    const float* __restrict__ dbih1, const float* __restrict__ dbhh1,
    const float* __restrict__ fcw, const float* __restrict__ fcb,
    float* __restrict__ dout, char* __restrict__ h0buf, char* __restrict__ h1buf,
    int* __restrict__ slots)
{
  __shared__ __align__(16) char upool[RG * XSTR * 2];  // enc: xe stage | dec: lbuf + w0d
  __shared__ __align__(16) f16 h0s[RG * HSTR];
  __shared__ __align__(16) f16 h1s[RG * HSTR];
  __shared__ __align__(16) f16 fcwb[ON * FSTR];
  __shared__ float gbuf0[RG * GSTR];
  __shared__ float gbuf1[RG * GSTR];
  __shared__ int amaxlds[RG];
  __shared__ int esc;

  f16*   xes  = (f16*)upool;
  float* lbuf = (float*)upool;            // [RG][33] logits (decoder only)
  float* w0d  = (float*)(upool + 4352);   // [64][32] dec_Wih0 slice (decoder only)

  const int tid  = threadIdx.x;
  const int g    = blockIdx.x & 7;        // batch group
  const int cg   = blockIdx.x >> 3;       // col-group within group, 0..31
  const int w    = tid >> 6;              // wave = gate index 0..3
  const int lane = tid & 63;
  const int quad = lane >> 4;
  const int l16  = lane & 15;
  const int colg = w * HN + cg * 16 + l16;  // global gate column (2048-space)
  const int urow = tid >> 3;              // pointwise: row 0..31
  const int ud0  = (tid & 7) * 2;         // pointwise: dim pair base
  int ctarget = 0;                        // cumulative counter-barrier target
  if (tid == 0) esc = 0;

  // ---- encoder weights -> register B-fragments
  f16x8 Wi0r[8], Wh0r[16], Wi1r[16], Wh1r[16];
  loadW<8>(eWih0, EN, colg, quad, Wi0r);
  loadW<16>(eWhh0, HN, colg, quad, Wh0r);
  loadW<16>(eWih1, HN, colg, quad, Wi1r);
  loadW<16>(eWhh1, HN, colg, quad, Wh1r);
  float bias0 = ebih0[colg] + ebhh0[colg];
  float bias1 = ebih1[colg] + ebhh1[colg];

  // ---- xe(0) pre-gather; zero h(-1) (parity 1); zero cell state
  gatherXE(xes, xTok, emb, g, 0, tid);
  float c0[2] = {0.f, 0.f}, c1[2] = {0.f, 0.f};
  {
    unsigned idx = (unsigned)(BN * 256 + (g * RG + urow) * 256 + cg * 8 + (tid & 7));
    __hip_atomic_store((unsigned*)h0buf + idx, 0u, __ATOMIC_RELAXED, __HIP_MEMORY_SCOPE_AGENT);
    __hip_atomic_store((unsigned*)h1buf + idx, 0u, __ATOMIC_RELAXED, __HIP_MEMORY_SCOPE_AGENT);
  }
  // ---- INIT barrier: proven flag protocol; also resets this group's counter.
  // Each wg's counter-reset store is ordered before its own flag by the vmcnt
  // drain, so "all flags set" implies "all resets visible". No counter adds
  // occur until after this barrier completes.
  __syncthreads();
  if (tid == 0) {
    __hip_atomic_store(&slots[g * 64 + 40], 0, __ATOMIC_RELAXED, __HIP_MEMORY_SCOPE_AGENT);
    asm volatile("s_waitcnt vmcnt(0)" ::: "memory");
    __hip_atomic_store(&slots[g * 64 + cg], 1, __ATOMIC_RELAXED, __HIP_MEMORY_SCOPE_AGENT);
  }
  if (!esc) {
    int idx = tid & 31;
    int gd = 0;
    for (;;) {
      int v = __hip_atomic_load(&slots[g * 64 + idx], __ATOMIC_RELAXED, __HIP_MEMORY_SCOPE_AGENT);
      if (__all(v >= 1)) break;
      if (++gd > POLL_GUARD) { esc = 1; break; }
      __builtin_amdgcn_s_sleep(1);
    }
  }
  __syncthreads();

  // ================= encoder: interval k does cell0@k + cell1@(k-1)
  for (int k = 0; k <= SN; ++k) {
    u32x4 v0[8], v1[8];
    issue8(v0, h0buf + (size_t)((k - 1) & 1) * BN * HN * 2 + (size_t)(g * RG) * HN * 2, tid);
    if (k >= 1)
      issue8(v1, h1buf + (size_t)(k & 1) * BN * HN * 2 + (size_t)(g * RG) * HN * 2, tid);

    f32x4 acc0[2], acc1[2];
    if (k < SN) {   // xe part of cell0 overlaps the stage loads
      f32x4 b0; b0[0] = bias0; b0[1] = bias0; b0[2] = bias0; b0[3] = bias0;
      acc0[0] = b0; acc0[1] = b0;
      matmulAcc<8>(acc0, xes, XSTR, Wi0r, l16, quad);
    }
    if (k >= 1) asm volatile("s_waitcnt vmcnt(8)" ::: "memory");  // h0 batch retired
    else        asm volatile("s_waitcnt vmcnt(0)" ::: "memory");
    write8(h0s, v0, tid);
    __syncthreads();
    if (k < SN) matmulAcc<16>(acc0, h0s, HSTR, Wh0r, l16, quad);   // h1 still in flight
    if (k >= 1) {
      f32x4 b1; b1[0] = bias1; b1[1] = bias1; b1[2] = bias1; b1[3] = bias1;
      acc1[0] = b1; acc1[1] = b1;
      matmulAcc<16>(acc1, h0s, HSTR, Wi1r, l16, quad);
      asm volatile("s_waitcnt vmcnt(0)" ::: "memory");
      write8(h1s, v1, tid);
      __syncthreads();
      matmulAcc<16>(acc1, h1s, HSTR, Wh1r, l16, quad);
    }

    // merged exchange: both cells, one sync, one pointwise pass
    #pragma unroll
    for (int mt = 0; mt < 2; ++mt) {
      #pragma unroll
      for (int i = 0; i < 4; ++i) {
        int rr = (mt * 16 + quad * 4 + i) * GSTR + w * 16 + l16;
        if (k < SN) gbuf0[rr] = acc0[mt][i];
        if (k >= 1) gbuf1[rr] = acc1[mt][i];
      }
    }
    __syncthreads();
    if (k < SN)
      pointwise_store(gbuf0, urow, ud0, c0,
                      (unsigned*)(h0buf + (size_t)(k & 1) * BN * HN * 2), g, cg, tid & 7);
    if (k >= 1)
      pointwise_store(gbuf1, urow, ud0, c1,
                      (unsigned*)(h1buf + (size_t)((k - 1) & 1) * BN * HN * 2), g, cg, tid & 7);

    arrive_ctr(slots, g, tid);
    if (k < SN - 1) gatherXE(xes, xTok, emb, g, k + 1, tid);   // hidden in the gap
    __syncthreads();   // gather-complete guard
    ctarget += NCG;
    wait_ctr(slots, g, ctarget, &esc);
  }

  // ================= decoder setup: swap weight regs to decoder weights
  loadW<16>(dWhh0, HN, colg, quad, Wh0r);
  loadW<16>(dWih1, HN, colg, quad, Wi1r);
  loadW<16>(dWhh1, HN, colg, quad, Wh1r);
  bias0 = dbih0[colg] + dbhh0[colg];
  bias1 = dbih1[colg] + dbhh1[colg];
  {   // dec_Wih0 slice [64 owned cols][32 inputs] -> LDS (one-hot gather table)
    int cl = tid >> 2, i0 = (tid & 3) * 8;
    int gcol = (cl >> 4) * HN + cg * 16 + (cl & 15);
    const float* p = dWih0 + (size_t)gcol * ON + i0;
    #pragma unroll
    for (int j = 0; j < 8; ++j) w0d[cl * 32 + i0 + j] = p[j];
  }
  if (tid < RG) amaxlds[tid] = 0;   // xin(0) = one-hot(0)
  // h0s holds h0@127 (staged at k=128); h1buf parity1 = h1@127; c0,c1 carry.

  // ================= decoder: I1 = [fc+softmax+amax@(t-1)] + cell0@t ; I2 = cell1@t
  for (int t = 0; t <= SN; ++t) {
    u32x4 v0[8];
    issue8(v0, h1buf + (size_t)((t - 1) & 1) * BN * HN * 2 + (size_t)(g * RG) * HN * 2, tid);
    float fb = 0.f;
    if (t >= 1) fb = fcb[(t - 1) * ON + ((w >> 1) * 16 + l16)];   // early, off-chain-ish

    f32x4 acc0[2];
    if (t < SN) {   // Whh0 part of cell0 (h0s ready) overlaps the h1 stage
      acc0[0] = f32x4{0.f, 0.f, 0.f, 0.f}; acc0[1] = acc0[0];
      matmulAcc<16>(acc0, h0s, HSTR, Wh0r, l16, quad);
    }
    asm volatile("s_waitcnt vmcnt(0)" ::: "memory");
    write8(h1s, v0, tid);
    __syncthreads();

    if (t >= 1) {
      int fmt = w & 1, fnt = w >> 1;
      int colo = fnt * 16 + l16;
      f32x4 afc = {0.f, 0.f, 0.f, 0.f};
      #pragma unroll
      for (int kt = 0; kt < 16; ++kt) {   // B-frags from LDS (prefetched in I2 gap)
        f16x8 bf = *(const f16x8*)&fcwb[colo * FSTR + kt * 32 + quad * 8];
        f16x8 av = *(const f16x8*)&h1s[(fmt * 16 + l16) * HSTR + kt * 32 + quad * 8];
        afc = MFMA16(av, bf, afc);
      }
      #pragma unroll
      for (int i = 0; i < 4; ++i)
        lbuf[(fmt * 16 + quad * 4 + i) * 33 + colo] = afc[i] + fb;
      __syncthreads();
      {   // parallel softmax + argmax: 8 threads per row, shfl_xor reductions
        int st = t - 1;
        int row = tid >> 3, s = tid & 7, cbase = s * 4;
        float vv[4];
        #pragma unroll
        for (int j = 0; j < 4; ++j) vv[j] = lbuf[row * 33 + cbase + j];
        float mx = vv[0]; int bi = cbase;
        #pragma unroll
        for (int j = 1; j < 4; ++j)
          if (vv[j] > mx) { mx = vv[j]; bi = cbase + j; }
        #pragma unroll
        for (int m = 1; m < 8; m <<= 1) {
          float om = __shfl_xor(mx, m);
          int   ob = __shfl_xor(bi, m);
          if (om > mx || (om == mx && ob < bi)) { mx = om; bi = ob; }
        }
        float e[4], ss = 0.f;
        #pragma unroll
        for (int j = 0; j < 4; ++j) { e[j] = __expf(vv[j] - mx); ss += e[j]; }
        #pragma unroll
        for (int m = 1; m < 8; m <<= 1) ss += __shfl_xor(ss, m);
        if (s == 0) amaxlds[row] = bi;
        if (cg == 0) {
          float inv = 1.0f / ss;
          float* op = dout + ((size_t)(g * RG + row) * SN + st) * ON + cbase;
          #pragma unroll
          for (int j = 0; j < 4; ++j) op[j] = e[j] * inv;
        }
      }
      __syncthreads();
    }

    if (t < SN) {   // add bias + one-hot gather(dec_Wih0, amax), then exchange
      #pragma unroll
      for (int mt = 0; mt < 2; ++mt) {
        #pragma unroll
        for (int i = 0; i < 4; ++i) {
          int row = mt * 16 + quad * 4 + i;
          acc0[mt][i] += bias0 + w0d[(w * 16 + l16) * 32 + amaxlds[row]];
        }
      }
      #pragma unroll
      for (int mt = 0; mt < 2; ++mt) {
        #pragma unroll
        for (int i = 0; i < 4; ++i)
          gbuf0[(mt * 16 + quad * 4 + i) * GSTR + w * 16 + l16] = acc0[mt][i];
      }
      __syncthreads();
      pointwise_store(gbuf0, urow, ud0, c0,
                      (unsigned*)(h0buf + (size_t)(t & 1) * BN * HN * 2), g, cg, tid & 7);
    }
    arrive_ctr(slots, g, tid);
    ctarget += NCG;
    wait_ctr(slots, g, ctarget, &esc);

    if (t < SN) {   // I2: cell1@t : h0@t@Wih1^T + h1@(t-1)@Whh1^T + b
      u32x4 v2[8];
      issue8(v2, h0buf + (size_t)(t & 1) * BN * HN * 2 + (size_t)(g * RG) * HN * 2, tid);
      f32x4 acc1[2];
      f32x4 b1; b1[0] = bias1; b1[1] = bias1; b1[2] = bias1; b1[3] = bias1;
      acc1[0] = b1; acc1[1] = b1;
      matmulAcc<16>(acc1, h1s, HSTR, Wh1r, l16, quad);   // h1@(t-1), overlaps stage
      asm volatile("s_waitcnt vmcnt(0)" ::: "memory");
      write8(h0s, v2, tid);
      __syncthreads();
      matmulAcc<16>(acc1, h0s, HSTR, Wi1r, l16, quad);
      #pragma unroll
      for (int mt = 0; mt < 2; ++mt) {
        #pragma unroll
        for (int i = 0; i < 4; ++i)
          gbuf0[(mt * 16 + quad * 4 + i) * GSTR + w * 16 + l16] = acc1[mt][i];
      }
      __syncthreads();
      pointwise_store(gbuf0, urow, ud0, c1,
                      (unsigned*)(h1buf + (size_t)(t & 1) * BN * HN * 2), g, cg, tid & 7);
      arrive_ctr(slots, g, tid);
      stageFCW(fcwb, fcw, t, tid);   // fcw[st=t] for next I1 — hidden in the gap
      __syncthreads();               // staging-complete guard
      ctarget += NCG;
      wait_ctr(slots, g, ctarget, &esc);
    }
  }
}

extern "C" void kernel_launch(void* const* d_in, const int* in_sizes, int n_in,
                              void* d_out, int out_size, void* d_ws, size_t ws_size,
                              hipStream_t stream) {
  (void)in_sizes; (void)n_in; (void)out_size; (void)ws_size;
  const int*   xTok  = (const int*)d_in[0];
  const float* emb   = (const float*)d_in[1];
  const float* eWih0 = (const float*)d_in[2];
  const float* eWhh0 = (const float*)d_in[3];
  const float* ebih0 = (const float*)d_in[4];
  const float* ebhh0 = (const float*)d_in[5];
  const float* eWih1 = (const float*)d_in[6];
  const float* eWhh1 = (const float*)d_in[7];
  const float* ebih1 = (const float*)d_in[8];
  const float* ebhh1 = (const float*)d_in[9];
  const float* dWih0 = (const float*)d_in[10];
  const float* dWhh0 = (const float*)d_in[11];
  const float* dbih0 = (const float*)d_in[12];
  const float* dbhh0 = (const float*)d_in[13];
  const float* dWih1 = (const float*)d_in[14];
  const float* dWhh1 = (const float*)d_in[15];
  const float* dbih1 = (const float*)d_in[16];
  const float* dbhh1 = (const float*)d_in[17];
  const float* fcw   = (const float*)d_in[18];
  const float* fcb   = (const float*)d_in[19];

  // ws layout (proven footprint): h0buf [2][256][512] f16 (512KB) |
  // h1buf (512KB) | slots [8][64] int (2KB; per group: flags 0..31 [init
  // barrier only], counter @40)
  char* h0buf = (char*)d_ws;
  char* h1buf = (char*)d_ws + (size_t)2 * BN * HN * 2;
  int*  slots = (int*)((char*)d_ws + (size_t)4 * BN * HN * 2);

  hipLaunchKernelGGL(lstm_all, dim3(256), dim3(NTHREADS), 0, stream,
                     xTok, emb, eWih0, eWhh0, ebih0, ebhh0, eWih1, eWhh1, ebih1, ebhh1,
                     dWih0, dWhh0, dbih0, dbhh0, dWih1, dWhh1, dbih1, dbhh1,
                     fcw, fcb, (float*)d_out, h0buf, h1buf, slots);
}